// Round 1
// baseline (1176.229 us; speedup 1.0000x reference)
//
#include <hip/hip_runtime.h>
#include <hip/hip_bf16.h>
#include <stdint.h>

typedef _Float16 h16_t;
typedef __attribute__((ext_vector_type(8))) _Float16 h16x8;
typedef __attribute__((ext_vector_type(4))) _Float16 h16x4;
typedef __attribute__((ext_vector_type(16))) float f32x16;

static constexpr int HDIM  = 2048;
static constexpr int MROWS = 8192;                   // 4 batches x 2048

// ---------------------------------------------------------------------------
__device__ __forceinline__ void gload_lds16(const h16_t* g, h16_t* l) {
  __builtin_amdgcn_global_load_lds(
      (const __attribute__((address_space(1))) void*)g,
      (__attribute__((address_space(3))) void*)l, 16, 0, 0);
}

__device__ __forceinline__ uint32_t ldsaddr(const void* p) {
  return (uint32_t)(uintptr_t)(const __attribute__((address_space(3))) void*)p;
}

__device__ __forceinline__ h16x8 dsread(uint32_t off) {
  h16x8 r;
  asm volatile("ds_read_b128 %0, %1" : "=v"(r) : "v"(off));
  return r;
}

__device__ __forceinline__ void sbar()  { __builtin_amdgcn_sched_barrier(0); }
__device__ __forceinline__ void bar()   { sbar(); __builtin_amdgcn_s_barrier(); sbar(); }
__device__ __forceinline__ void waitlg0(){ asm volatile("s_waitcnt lgkmcnt(0)" ::: "memory"); sbar(); }
__device__ __forceinline__ void waitvm4(){ asm volatile("s_waitcnt vmcnt(4)" ::: "memory"); sbar(); }
__device__ __forceinline__ void waitvm0(){ asm volatile("s_waitcnt vmcnt(0)" ::: "memory"); sbar(); }

// ===========================================================================
// OLD 128x128 core (m97-structure) — kept for the small weight-fold GEMMs
// where launch packing (256 blocks of 128^2) beats the big-tile kernel.
// ===========================================================================
__device__ __forceinline__ void gemm_core(const h16_t* __restrict__ A,
                                          const h16_t* __restrict__ B,
                                          f32x16 acc[2][2],
                                          h16_t* sA, h16_t* sB) {
  const int tid  = threadIdx.x;
  const int wid  = tid >> 6;
  const int lane = tid & 63;
  const int wr  = (wid >> 1) << 6;
  const int wc  = (wid & 1) << 6;
  const int l31 = lane & 31;
  const int hi  = lane >> 5;
  const int sx  = lane & 7;

#pragma unroll
  for (int i = 0; i < 2; i++)
#pragma unroll
    for (int j = 0; j < 2; j++)
#pragma unroll
      for (int r = 0; r < 16; r++) acc[i][j][r] = 0.0f;

  for (int k0 = 0; k0 < 2048; k0 += 64) {
    __syncthreads();
#pragma unroll
    for (int rnd = 0; rnd < 4; rnd++) {
      const int cid  = rnd * 256 + tid;
      const int row  = cid >> 3;
      const int koct = (cid & 7) ^ (row & 7);
      const long long goff = (long long)row * 2048 + k0 + koct * 8;
      gload_lds16(A + goff, sA + (rnd * 256 + wid * 64) * 8);
      gload_lds16(B + goff, sB + (rnd * 256 + wid * 64) * 8);
    }
    __syncthreads();

#pragma unroll
    for (int ko = 0; ko < 4; ko++) {
      const int po = (2 * ko + hi) ^ sx;
      h16x8 fa[2], fb[2];
#pragma unroll
      for (int i = 0; i < 2; i++)
        fa[i] = *(const h16x8*)(sA + (wr + i * 32 + l31) * 64 + po * 8);
#pragma unroll
      for (int j = 0; j < 2; j++)
        fb[j] = *(const h16x8*)(sB + (wc + j * 32 + l31) * 64 + po * 8);
#pragma unroll
      for (int i = 0; i < 2; i++)
#pragma unroll
        for (int j = 0; j < 2; j++)
          acc[i][j] = __builtin_amdgcn_mfma_f32_32x32x16_f16(
              fa[i], fb[j], acc[i][j], 0, 0, 0);
    }
  }
}

__device__ __forceinline__ void store_c(h16_t* __restrict__ C,
                                        f32x16 acc[2][2], int bm, int bn) {
  const int tid  = threadIdx.x;
  const int wid  = tid >> 6;
  const int lane = tid & 63;
  const int wr = (wid >> 1) << 6, wc = (wid & 1) << 6;
  const int l31 = lane & 31, hi = lane >> 5;
  const int gr = bm * 128 + wr + 4 * hi;
  const int gc = bn * 128 + wc + l31;
#pragma unroll
  for (int i = 0; i < 2; i++)
#pragma unroll
    for (int r = 0; r < 16; r++) {
      const int row = gr + i * 32 + (r & 3) + 8 * (r >> 2);
      const long long ro = (long long)row * 2048;
#pragma unroll
      for (int j = 0; j < 2; j++)
        C[ro + gc + j * 32] = (h16_t)acc[i][j][r];
    }
}

__global__ __launch_bounds__(256)
void gemm_b(const h16_t* __restrict__ Ab, const h16_t* __restrict__ Bb,
            h16_t* __restrict__ Cb, long long sAz, long long sBz, long long sCz)
{
  __shared__ __align__(16) h16_t sA[128 * 64];
  __shared__ __align__(16) h16_t sB[128 * 64];
  const int bn = blockIdx.x, bm = blockIdx.y, z = blockIdx.z;
  const h16_t* A = Ab + (long long)z * sAz + (long long)bm * 128 * 2048;
  const h16_t* B = Bb + (long long)z * sBz + (long long)bn * 128 * 2048;
  f32x16 acc[2][2];
  gemm_core(A, B, acc, sA, sB);
  store_c(Cb + (long long)z * sCz, acc, bm, bn);
}

// ===========================================================================
// NEW 256x256 8-phase core (m201 structure, plain HIP + inline asm):
//  - BK=64, 512 threads = 8 waves (2M x 4N), wave tile 128x64, 32x32x16 MFMA
//  - 128 KiB LDS: [A0|B0|A1|B1], XOR-octet swizzle applied on global src
//  - raw s_barrier, counted s_waitcnt vmcnt(4) once per K-tile (never 0 in
//    main loop), asm ds_read_b128 + lgkmcnt(0) + sched_barrier (rule #18),
//    s_setprio(1) around each 8-MFMA cluster.
//  - Frag reads confined to phases 0/1 of each tile so phases 2/3 may issue
//    the tile t+2 prefetch into the *current* buffer: any wave issuing that
//    stage has passed the phase-1 end-barrier, which every wave reaches only
//    after its own lgkmcnt(0) -> all reads of this buffer are complete.
// Pipeline (tile t even -> buf0, odd -> buf1); per tile:
//   p0: read A-M0(8),B-N0(4); stage B(t+1) chunks 0,1 ; bar; lg0; MFMA(M0,N0)
//   p1: read B-N1(4),A-M1(8); stage B(t+1) chunks 2,3 ; bar; lg0; MFMA(M0,N1)
//   p2:                      stage A(t+2) chunks 0,1 ; bar;      MFMA(M1,N1)
//   p3:                      stage A(t+2) chunks 2,3 ; bar;      MFMA(M1,N0)
//       vmcnt(4) (= leave next A-panel in flight) ; bar
// ===========================================================================
__device__ __forceinline__ void core256(const h16_t* __restrict__ A,
                                        const h16_t* __restrict__ B,
                                        h16_t* smem, f32x16 acc[4][2])
{
  const int tid  = threadIdx.x;
  const int wid  = tid >> 6, lane = tid & 63;
  const int wr2  = wid >> 2, wcid = wid & 3;
  const int l31  = lane & 31, hi = lane >> 5, sx = lane & 7;

  h16_t* pA[2] = { smem,          smem + 32768 };
  h16_t* pB[2] = { smem + 16384,  smem + 49152 };

  // LDS read bases (byte offsets). Physical octet = logical ^ (row&7).
  uint32_t poB[4];
#pragma unroll
  for (int ks = 0; ks < 4; ks++) poB[ks] = (uint32_t)((((2 * ks + hi) ^ sx) << 4));
  const uint32_t lrow = (uint32_t)(l31 * 128);
  uint32_t aT[2], bT[2];
#pragma unroll
  for (int b = 0; b < 2; b++) {
    aT[b] = ldsaddr(pA[b]) + (uint32_t)(wr2 * 128 * 128) + lrow;
    bT[b] = ldsaddr(pB[b]) + (uint32_t)(wcid * 64 * 128) + lrow;
  }

  // staging constants: chunk ci covers rows [ci*64, ci*64+64); thread holds
  // octet (tid&7), row ci*64+(tid>>3); global k-octet = oct ^ (row&7).
  const int srow = tid >> 3;
  const long long stOff = (long long)srow * HDIM + (long long)(((tid & 7) ^ (srow & 7)) * 8);
  const int dOff = tid * 8;

  auto stage2 = [&](const h16_t* M, h16_t* panel, int k0, int ci0) {
#pragma unroll
    for (int c = 0; c < 2; c++) {
      const int ci = ci0 + c;
      gload_lds16(M + stOff + k0 + (long long)ci * (64 * HDIM),
                  panel + ci * 4096 + dOff);
    }
  };

#pragma unroll
  for (int i = 0; i < 4; i++)
#pragma unroll
    for (int j = 0; j < 2; j++)
#pragma unroll
      for (int r = 0; r < 16; r++) acc[i][j][r] = 0.0f;

  h16x8 fa0[2][4], fa1[2][4], fb0[4], fb1[4];

  auto rdA = [&](h16x8 (&fa)[2][4], uint32_t base) {
#pragma unroll
    for (int mi = 0; mi < 2; mi++)
#pragma unroll
      for (int ks = 0; ks < 4; ks++)
        fa[mi][ks] = dsread(base + (uint32_t)(mi * 32 * 128) + poB[ks]);
  };
  auto rdB = [&](h16x8 (&fb)[4], uint32_t base) {
#pragma unroll
    for (int ks = 0; ks < 4; ks++) fb[ks] = dsread(base + poB[ks]);
  };
  auto mm8 = [&](int am0, int nj, h16x8 (&fa)[2][4], h16x8 (&fb)[4]) {
#pragma unroll
    for (int ks = 0; ks < 4; ks++)
#pragma unroll
      for (int mi = 0; mi < 2; mi++)
        acc[am0 + mi][nj] = __builtin_amdgcn_mfma_f32_32x32x16_f16(
            fa[mi][ks], fb[ks], acc[am0 + mi][nj], 0, 0, 0);
  };

  // tailmode: 0 = vmcnt(4)+bar, 1 = vmcnt(0)+bar, 2 = bar only
  auto tile4 = [&](int buf, h16_t* stB, int kB, bool doB,
                   h16_t* stA, int kA, bool doA, int tailmode) {
    // ---- p0
    rdA(fa0, aT[buf]);
    rdB(fb0, bT[buf]);
    if (doB) stage2(B, stB, kB, 0);
    bar(); waitlg0();
    __builtin_amdgcn_s_setprio(1); mm8(0, 0, fa0, fb0); __builtin_amdgcn_s_setprio(0);
    bar();
    // ---- p1
    rdB(fb1, bT[buf] + 4096);
    rdA(fa1, aT[buf] + 8192);
    if (doB) stage2(B, stB, kB, 2);
    bar(); waitlg0();
    __builtin_amdgcn_s_setprio(1); mm8(0, 1, fa0, fb1); __builtin_amdgcn_s_setprio(0);
    bar();
    // ---- p2
    if (doA) stage2(A, stA, kA, 0);
    bar();
    __builtin_amdgcn_s_setprio(1); mm8(2, 1, fa1, fb1); __builtin_amdgcn_s_setprio(0);
    bar();
    // ---- p3
    if (doA) stage2(A, stA, kA, 2);
    bar();
    __builtin_amdgcn_s_setprio(1); mm8(2, 0, fa1, fb0); __builtin_amdgcn_s_setprio(0);
    if (tailmode == 0) waitvm4(); else if (tailmode == 1) waitvm0();
    bar();
  };

  // prologue: A(t0), B(t0), A(t1); keep A(t1) in flight
  stage2(A, pA[0], 0, 0);  stage2(A, pA[0], 0, 2);
  stage2(B, pB[0], 0, 0);  stage2(B, pB[0], 0, 2);
  stage2(A, pA[1], 64, 0); stage2(A, pA[1], 64, 2);
  waitvm4(); bar();

#pragma unroll 1
  for (int t = 0; t < 30; t += 2) {
    tile4(0, pB[1], (t + 1) * 64, true, pA[0], (t + 2) * 64, true, 0);
    tile4(1, pB[0], (t + 2) * 64, true, pA[1], (t + 3) * 64, true, 0);
  }
  // t = 30/31 tail
  tile4(0, pB[1], 31 * 64, true, nullptr, 0, false, 1);
  tile4(1, nullptr, 0, false, nullptr, 0, false, 2);
}

// C/D layout 32x32 (HW-verified): col=lane&31, row=(reg&3)+8*(reg>>2)+4*hi
__device__ __forceinline__ void store256(h16_t* __restrict__ C,
                                         f32x16 acc[4][2], int bm, int bn)
{
  const int tid = threadIdx.x, wid = tid >> 6, lane = tid & 63;
  const int wr2 = wid >> 2, wcid = wid & 3;
  const int l31 = lane & 31, hi = lane >> 5;
  const int gr0 = bm * 256 + wr2 * 128 + 4 * hi;
  const int gc0 = bn * 256 + wcid * 64 + l31;
#pragma unroll
  for (int am = 0; am < 4; am++)
#pragma unroll
    for (int r = 0; r < 16; r++) {
      const int row = gr0 + am * 32 + (r & 3) + 8 * (r >> 2);
      const long long ro = (long long)row * HDIM;
#pragma unroll
      for (int nj = 0; nj < 2; nj++)
        C[ro + gc0 + nj * 32] = (h16_t)acc[am][nj][r];
    }
}

// ---------------------------------------------------------------------------
__global__ __launch_bounds__(512, 2)
void gemm256_b(const h16_t* __restrict__ Ab, const h16_t* __restrict__ Bb,
               h16_t* __restrict__ Cb, long long sAz, long long sBz, long long sCz)
{
  __shared__ __align__(16) h16_t smem[4 * 16384];
  const int bn = blockIdx.x, bm = blockIdx.y, z = blockIdx.z;
  const h16_t* A = Ab + (long long)z * sAz + (long long)bm * 256 * HDIM;
  const h16_t* B = Bb + (long long)z * sBz + (long long)bn * 256 * HDIM;
  f32x16 acc[4][2];
  core256(A, B, smem, acc);
  store256(Cb + (long long)z * sCz, acc, bm, bn);
}

// uT GEMM (z<4) + in-place softmax of sc rows (z>=4, 8 rows per block,
// one full 2048-row per 64-lane wave, 32 f16/lane).
__global__ __launch_bounds__(512, 2)
void gemm256_ut_softmax(const h16_t* __restrict__ Wvow, const h16_t* __restrict__ xb,
                        h16_t* __restrict__ ut, h16_t* __restrict__ sc)
{
  const int bn = blockIdx.x, bm = blockIdx.y, z = blockIdx.z;
  const int tid = threadIdx.x;
  if (z >= 4) {
    const int wid = tid >> 6, lane = tid & 63;
    const long long row = (long long)(z - 4) * 512 + (bm * 8 + bn) * 8 + wid;
    h16_t* s = sc + row * HDIM;
    h16x8 raw[4];
#pragma unroll
    for (int i = 0; i < 4; i++) raw[i] = ((const h16x8*)s)[i * 64 + lane];
    float v[32];
    float mx = -3.0e38f;
#pragma unroll
    for (int i = 0; i < 32; i++) { v[i] = (float)raw[i >> 3][i & 7]; mx = fmaxf(mx, v[i]); }
#pragma unroll
    for (int off = 32; off; off >>= 1) mx = fmaxf(mx, __shfl_xor(mx, off, 64));
    float sum = 0.f;
#pragma unroll
    for (int i = 0; i < 32; i++) { v[i] = __expf(v[i] - mx); sum += v[i]; }
#pragma unroll
    for (int off = 32; off; off >>= 1) sum += __shfl_xor(sum, off, 64);
    const float inv = 1.0f / sum;
#pragma unroll
    for (int i = 0; i < 4; i++) {
      h16x8 o;
#pragma unroll
      for (int j = 0; j < 8; j++) o[j] = (h16_t)(v[i * 8 + j] * inv);
      ((h16x8*)s)[i * 64 + lane] = o;
    }
    return;
  }
  __shared__ __align__(16) h16_t smem[4 * 16384];
  const h16_t* A = Wvow + (long long)bm * 256 * HDIM;
  const h16_t* B = xb + (long long)z * (long long)HDIM * HDIM + (long long)bn * 256 * HDIM;
  f32x16 acc[4][2];
  core256(A, B, smem, acc);
  store256(ut + (long long)z * (long long)HDIM * HDIM, acc, bm, bn);
}

// final: out += sum relu(P @ u) . colsum(W2)
__global__ __launch_bounds__(512, 2)
void gemm256_final(const h16_t* __restrict__ P, const h16_t* __restrict__ utb,
                   const float* __restrict__ w2p, float* __restrict__ outp)
{
  __shared__ __align__(16) h16_t smem[4 * 16384];
  const int bn = blockIdx.x, bm = blockIdx.y, z = blockIdx.z;
  const long long HH = (long long)HDIM * HDIM;
  const h16_t* A = P   + (long long)z * HH + (long long)bm * 256 * HDIM;
  const h16_t* B = utb + (long long)z * HH + (long long)bn * 256 * HDIM;
  f32x16 acc[4][2];
  core256(A, B, smem, acc);

  const int tid = threadIdx.x, wid = tid >> 6, lane = tid & 63;
  const int wcid = wid & 3, l31 = lane & 31;
  const int gc0 = bn * 256 + wcid * 64 + l31;
  float w2j[2];
#pragma unroll
  for (int nj = 0; nj < 2; nj++) {
    const int col = gc0 + nj * 32;
    float s = 0.f;
#pragma unroll
    for (int c = 0; c < 16; c++) s += w2p[c * HDIM + col];
    w2j[nj] = s;
  }
  float s = 0.f;
#pragma unroll
  for (int am = 0; am < 4; am++)
#pragma unroll
    for (int nj = 0; nj < 2; nj++)
#pragma unroll
      for (int r = 0; r < 16; r++) {
        const float vv = acc[am][nj][r];
        s += (vv > 0.f) ? vv * w2j[nj] : 0.f;
      }
#pragma unroll
  for (int off = 32; off; off >>= 1) s += __shfl_down(s, off, 64);
  __shared__ float red[8];
  if (lane == 0) red[wid] = s;
  __syncthreads();
  if (tid == 0) {
    float t = 0.f;
#pragma unroll
    for (int w = 0; w < 8; w++) t += red[w];
    atomicAdd(outp, t);
  }
}

// ---------------------------------------------------------------------------
// mega-prologue: one launch for all converts / transposes / colsum / zero.
__global__ __launch_bounds__(256)
void prologue_kernel(const float* __restrict__ x,  const float* __restrict__ Wq,
                     const float* __restrict__ Wk, const float* __restrict__ Wv,
                     const float* __restrict__ Wo, const float* __restrict__ W1,
                     const float* __restrict__ W2,
                     h16_t* __restrict__ xb,  h16_t* __restrict__ WkT,
                     h16_t* __restrict__ WvT, h16_t* __restrict__ WqT,
                     h16_t* __restrict__ Wob, h16_t* __restrict__ W1b,
                     float* __restrict__ w2p, float* __restrict__ outp)
{
  const int t = threadIdx.x;
  int b = blockIdx.x;
  if (b < 16384) {                       // x: fp32 -> f16, 4/thread
    const long long i = (long long)b * 256 + t;
    const float4 v = ((const float4*)x)[i];
    h16x4 o;
    o[0] = (h16_t)v.x; o[1] = (h16_t)v.y; o[2] = (h16_t)v.z; o[3] = (h16_t)v.w;
    ((h16x4*)xb)[i] = o;
    return;
  }
  b -= 16384;
  if (b < 12288) {                       // Wk,Wv,Wq transposed converts
    const float* src; h16_t* dst;
    if (b < 4096)      { src = Wk; dst = WkT; }
    else if (b < 8192) { src = Wv; dst = WvT; b -= 4096; }
    else               { src = Wq; dst = WqT; b -= 8192; }
    __shared__ float tl[32][33];
    const int bx = (b & 63) * 32, by = (b >> 6) * 32;
    const int xx = t & 31, y0 = t >> 5;
    for (int y = y0; y < 32; y += 8)
      tl[y][xx] = src[(long long)(by + y) * 2048 + bx + xx];
    __syncthreads();
    for (int y = y0; y < 32; y += 8)
      dst[(long long)(bx + y) * 2048 + by + xx] = (h16_t)tl[xx][y];
    return;
  }
  b -= 12288;
  if (b < 8192) {                        // Wo, W1 plain converts
    const float* src = (b < 4096) ? Wo : W1;
    h16_t* dst = (b < 4096) ? Wob : W1b;
    const long long i = (long long)(b & 4095) * 256 + t;
    const float4 v = ((const float4*)src)[i];
    h16x4 o;
    o[0] = (h16_t)v.x; o[1] = (h16_t)v.y; o[2] = (h16_t)v.z; o[3] = (h16_t)v.w;
    ((h16x4*)dst)[i] = o;
    return;
  }
  b -= 8192;
  if (b < 128) {                         // W2 colsum partials (non-atomic)
    const int c = b >> 3;
    const int h = (b & 7) * 256 + t;
    float s = 0.f;
#pragma unroll 4
    for (int d = 0; d < 128; d++) s += W2[(long long)(c * 128 + d) * 2048 + h];
    w2p[c * 2048 + h] = s;
    return;
  }
  b -= 128;
  if (b == 0 && t == 0) outp[0] = 0.f;   // zero the output accumulator
}

// ---------------------------------------------------------------------------
extern "C" void kernel_launch(void* const* d_in, const int* in_sizes, int n_in,
                              void* d_out, int out_size, void* d_ws, size_t ws_size,
                              hipStream_t stream)
{
  const float* x  = (const float*)d_in[0];
  const float* Wq = (const float*)d_in[1];
  const float* Wk = (const float*)d_in[2];
  const float* Wv = (const float*)d_in[3];
  const float* Wo = (const float*)d_in[4];
  const float* W1 = (const float*)d_in[5];
  const float* W2 = (const float*)d_in[6];
  float* out = (float*)d_out;

  const long long HH = (long long)HDIM * HDIM;   // 4,194,304
  const long long XE = (long long)MROWS * HDIM;  // 16,777,216

  // Algebra: score = x (Wq^T Wk) x^T;  h = relu(P x (W1 Wo Wv)^T);
  //          out = sum h.colsum(W2)
  char* p = (char*)d_ws;
  h16_t* xb   = (h16_t*)p; p += XE * 2;
  h16_t* WkT  = (h16_t*)p; p += HH * 2;
  h16_t* WvT  = (h16_t*)p; p += HH * 2;
  h16_t* WqT  = (h16_t*)p; p += HH * 2;
  h16_t* Wob  = (h16_t*)p; p += HH * 2;
  h16_t* WqkT = (h16_t*)p; p += HH * 2;
  h16_t* GT   = (h16_t*)p; p += HH * 2;
  h16_t* W1b  = (h16_t*)p; p += HH * 2;
  h16_t* Wvow = (h16_t*)p; p += HH * 2;
  h16_t* tb   = (h16_t*)p; p += XE * 2;  // t, then uT
  h16_t* sc   = (h16_t*)p; p += XE * 2;  // score -> P in place
  float* w2p  = (float*)p; p += 16 * HDIM * 4;

  const dim3 b256(256), b512(512);

  // 1. mega-prologue: converts, transposes, colsum, zero-out
  prologue_kernel<<<dim3(16384 + 12288 + 8192 + 128 + 1), b256, 0, stream>>>(
      x, Wq, Wk, Wv, Wo, W1, W2, xb, WkT, WvT, WqT, Wob, W1b, w2p, out);

  // 2. batched fold: WqkT = (Wq^T Wk)^T ; GT = (Wo Wv)^T   (128^2 kernel)
  gemm_b<<<dim3(16, 16, 2), b256, 0, stream>>>(WkT, WqT, WqkT, HH, HH, HH);

  // 3. Wvow = W1.G fold (128^2 kernel, 256 balanced blocks)
  gemm_b<<<dim3(16, 16, 1), b256, 0, stream>>>(W1b, GT, Wvow, 0, 0, 0);

  // 4. t = x@Wqk   (256^2 8-phase, 8x32 = 256 blocks, 1/CU)
  gemm256_b<<<dim3(8, 32, 1), b512, 0, stream>>>(xb, WqkT, tb, 0, 0, 0);

  // 5. score[b,i,j] = sum_e t[b,i,e]*x[b,j,e]   (256 blocks)
  gemm256_b<<<dim3(8, 8, 4), b512, 0, stream>>>(tb, xb, sc, HH, HH, HH);

  // 6. uT[b,e,j] = sum_h Wvow[e,h]*x[b,j,h] (z<4, into tb) + softmax(sc) (z>=4)
  gemm256_ut_softmax<<<dim3(8, 8, 20), b512, 0, stream>>>(Wvow, xb, tb, sc);

  // 7. out += sum relu(P @ u) . w2
  gemm256_final<<<dim3(8, 8, 4), b512, 0, stream>>>(sc, tb, w2p, out);
}

// Round 2
// 550.997 us; speedup vs baseline: 2.1347x; 2.1347x over previous
//
#include <hip/hip_runtime.h>
#include <hip/hip_bf16.h>
#include <stdint.h>

typedef _Float16 h16_t;
typedef __attribute__((ext_vector_type(8))) _Float16 h16x8;
typedef __attribute__((ext_vector_type(4))) _Float16 h16x4;
typedef __attribute__((ext_vector_type(16))) float f32x16;

static constexpr int HDIM  = 2048;
static constexpr int MROWS = 8192;                   // 4 batches x 2048

// ---------------------------------------------------------------------------
__device__ __forceinline__ void gload_lds16(const h16_t* g, h16_t* l) {
  __builtin_amdgcn_global_load_lds(
      (const __attribute__((address_space(1))) void*)g,
      (__attribute__((address_space(3))) void*)l, 16, 0, 0);
}

__device__ __forceinline__ uint32_t ldsaddr(const void* p) {
  return (uint32_t)(uintptr_t)(const __attribute__((address_space(3))) void*)p;
}

__device__ __forceinline__ h16x8 dsread(uint32_t off) {
  h16x8 r;
  asm volatile("ds_read_b128 %0, %1" : "=v"(r) : "v"(off));
  return r;
}

__device__ __forceinline__ void sbar()  { __builtin_amdgcn_sched_barrier(0); }
__device__ __forceinline__ void bar()   { sbar(); __builtin_amdgcn_s_barrier(); sbar(); }
__device__ __forceinline__ void waitlg0(){ asm volatile("s_waitcnt lgkmcnt(0)" ::: "memory"); sbar(); }
__device__ __forceinline__ void waitvm4(){ asm volatile("s_waitcnt vmcnt(4)" ::: "memory"); sbar(); }
__device__ __forceinline__ void waitvm0(){ asm volatile("s_waitcnt vmcnt(0)" ::: "memory"); sbar(); }

// ===========================================================================
// OLD 128x128 core (m97-structure) — kept for the small weight-fold GEMMs
// (launch packing: 512/256 blocks of 128^2 fill all CUs; 256^2 would idle
// half the chip on a 2048^2 output).
// ===========================================================================
__device__ __forceinline__ void gemm_core(const h16_t* __restrict__ A,
                                          const h16_t* __restrict__ B,
                                          f32x16 acc[2][2],
                                          h16_t* sA, h16_t* sB) {
  const int tid  = threadIdx.x;
  const int wid  = tid >> 6;
  const int lane = tid & 63;
  const int wr  = (wid >> 1) << 6;
  const int wc  = (wid & 1) << 6;
  const int l31 = lane & 31;
  const int hi  = lane >> 5;
  const int sx  = lane & 7;

#pragma unroll
  for (int i = 0; i < 2; i++)
#pragma unroll
    for (int j = 0; j < 2; j++)
#pragma unroll
      for (int r = 0; r < 16; r++) acc[i][j][r] = 0.0f;

  for (int k0 = 0; k0 < 2048; k0 += 64) {
    __syncthreads();
#pragma unroll
    for (int rnd = 0; rnd < 4; rnd++) {
      const int cid  = rnd * 256 + tid;
      const int row  = cid >> 3;
      const int koct = (cid & 7) ^ (row & 7);
      const long long goff = (long long)row * 2048 + k0 + koct * 8;
      gload_lds16(A + goff, sA + (rnd * 256 + wid * 64) * 8);
      gload_lds16(B + goff, sB + (rnd * 256 + wid * 64) * 8);
    }
    __syncthreads();

#pragma unroll
    for (int ko = 0; ko < 4; ko++) {
      const int po = (2 * ko + hi) ^ sx;
      h16x8 fa[2], fb[2];
#pragma unroll
      for (int i = 0; i < 2; i++)
        fa[i] = *(const h16x8*)(sA + (wr + i * 32 + l31) * 64 + po * 8);
#pragma unroll
      for (int j = 0; j < 2; j++)
        fb[j] = *(const h16x8*)(sB + (wc + j * 32 + l31) * 64 + po * 8);
#pragma unroll
      for (int i = 0; i < 2; i++)
#pragma unroll
        for (int j = 0; j < 2; j++)
          acc[i][j] = __builtin_amdgcn_mfma_f32_32x32x16_f16(
              fa[i], fb[j], acc[i][j], 0, 0, 0);
    }
  }
}

__device__ __forceinline__ void store_c(h16_t* __restrict__ C,
                                        f32x16 acc[2][2], int bm, int bn) {
  const int tid  = threadIdx.x;
  const int wid  = tid >> 6;
  const int lane = tid & 63;
  const int wr = (wid >> 1) << 6, wc = (wid & 1) << 6;
  const int l31 = lane & 31, hi = lane >> 5;
  const int gr = bm * 128 + wr + 4 * hi;
  const int gc = bn * 128 + wc + l31;
#pragma unroll
  for (int i = 0; i < 2; i++)
#pragma unroll
    for (int r = 0; r < 16; r++) {
      const int row = gr + i * 32 + (r & 3) + 8 * (r >> 2);
      const long long ro = (long long)row * 2048;
#pragma unroll
      for (int j = 0; j < 2; j++)
        C[ro + gc + j * 32] = (h16_t)acc[i][j][r];
    }
}

__global__ __launch_bounds__(256)
void gemm_b(const h16_t* __restrict__ Ab, const h16_t* __restrict__ Bb,
            h16_t* __restrict__ Cb, long long sAz, long long sBz, long long sCz)
{
  __shared__ __align__(16) h16_t sA[128 * 64];
  __shared__ __align__(16) h16_t sB[128 * 64];
  const int bn = blockIdx.x, bm = blockIdx.y, z = blockIdx.z;
  const h16_t* A = Ab + (long long)z * sAz + (long long)bm * 128 * 2048;
  const h16_t* B = Bb + (long long)z * sBz + (long long)bn * 128 * 2048;
  f32x16 acc[2][2];
  gemm_core(A, B, acc, sA, sB);
  store_c(Cb + (long long)z * sCz, acc, bm, bn);
}

// ===========================================================================
// 256x256 8-phase core, v2 (register-lean).
// Changes vs v1 (which spilled: 128 AGPR acc + 96 VGPR frags + addr > 256
// unified regs -> scratch, 22MB phantom WRITE_SIZE, MfmaUtil 11%):
//  - ONE A-fragment array fA[2][4] (32 VGPR), reused: rows [0,64) of the
//    wave tile read in p0, rows [64,128) overwrite it in p2 (after last use
//    in p1). fB0/fB1 16 VGPR each. Peak frag regs 64 (was 96).
//  - balanced reads: p0=12, p1=4, p2=8, p3=0 ds_read_b128.
//  - A(t+2) staged chunks {0,2} in p2 (read+drained in p0, two barriers
//    earlier), chunks {1,3} in p3 (drained in p2). B(t+1) -> other buffer.
//  - counted vmcnt(4) once per K-tile (leaves next A panel in flight),
//    never 0 in the main loop; raw s_barrier; lgkmcnt(0)+sched_barrier
//    before MFMA (rule #18); s_setprio(1) around each 8-MFMA cluster.
// ===========================================================================
__device__ __forceinline__ void core256(const h16_t* __restrict__ A,
                                        const h16_t* __restrict__ B,
                                        h16_t* smem, f32x16 acc[4][2])
{
  const int tid  = threadIdx.x;
  const int wid  = tid >> 6, lane = tid & 63;
  const int wr2  = wid >> 2, wcid = wid & 3;
  const int l31  = lane & 31, hi = lane >> 5, sx = lane & 7;

  h16_t* pA[2] = { smem,          smem + 32768 };   // 32KB panels
  h16_t* pB[2] = { smem + 16384,  smem + 49152 };

  uint32_t poB[4];
#pragma unroll
  for (int ks = 0; ks < 4; ks++) poB[ks] = (uint32_t)((((2 * ks + hi) ^ sx) << 4));
  const uint32_t lrow = (uint32_t)(l31 * 128);
  const uint32_t aT0 = ldsaddr(pA[0]) + (uint32_t)(wr2 * 16384) + lrow;
  const uint32_t aT1 = ldsaddr(pA[1]) + (uint32_t)(wr2 * 16384) + lrow;
  const uint32_t bT0 = ldsaddr(pB[0]) + (uint32_t)(wcid * 8192) + lrow;
  const uint32_t bT1 = ldsaddr(pB[1]) + (uint32_t)(wcid * 8192) + lrow;

  // staging: chunk ci = panel rows [ci*64, ci*64+64); this thread stages the
  // 16B octet (tid&7)^(row&7) of row ci*64+(tid>>3); LDS dst is linear.
  const int srow = tid >> 3;
  const long long stOff = (long long)srow * HDIM + (long long)(((tid & 7) ^ (srow & 7)) * 8);
  const int dOff = tid * 8;

  auto stage1 = [&](const h16_t* M, h16_t* panel, int k0, int ci) {
    gload_lds16(M + stOff + k0 + (long long)ci * (64 * HDIM),
                panel + ci * 4096 + dOff);
  };

#pragma unroll
  for (int i = 0; i < 4; i++)
#pragma unroll
    for (int j = 0; j < 2; j++)
#pragma unroll
      for (int r = 0; r < 16; r++) acc[i][j][r] = 0.0f;

  h16x8 fA[2][4], fB0[4], fB1[4];

  auto rdA = [&](uint32_t base) {            // 8 reads -> fA (overwrites)
#pragma unroll
    for (int mi = 0; mi < 2; mi++)
#pragma unroll
      for (int ks = 0; ks < 4; ks++)
        fA[mi][ks] = dsread(base + (uint32_t)(mi * 4096) + poB[ks]);
  };
  auto rdB = [&](h16x8 (&fb)[4], uint32_t base) {  // 4 reads
#pragma unroll
    for (int ks = 0; ks < 4; ks++) fb[ks] = dsread(base + poB[ks]);
  };
  auto mm8 = [&](int am0, int nj, h16x8 (&fb)[4]) {
#pragma unroll
    for (int ks = 0; ks < 4; ks++)
#pragma unroll
      for (int mi = 0; mi < 2; mi++)
        acc[am0 + mi][nj] = __builtin_amdgcn_mfma_f32_32x32x16_f16(
            fA[mi][ks], fb[ks], acc[am0 + mi][nj], 0, 0, 0);
  };

  // tailmode: 0 = vmcnt(4)+bar, 1 = vmcnt(0)+bar, 2 = bar only
  auto tile4 = [&](uint32_t aT, uint32_t bT, h16_t* pAcur,
                   h16_t* stB, int kB, bool doB,
                   int kA, bool doA, int tailmode) {
    // ---- p0: A rows [0,64), B cols [0,32); stage B(t+1) chunks 0,1
    rdA(aT);
    rdB(fB0, bT);
    if (doB) { stage1(B, stB, kB, 0); stage1(B, stB, kB, 1); }
    bar(); waitlg0();
    __builtin_amdgcn_s_setprio(1); mm8(0, 0, fB0); __builtin_amdgcn_s_setprio(0);
    bar();
    // ---- p1: B cols [32,64); stage B(t+1) chunks 2,3
    rdB(fB1, bT + 4096);
    if (doB) { stage1(B, stB, kB, 2); stage1(B, stB, kB, 3); }
    bar(); waitlg0();
    __builtin_amdgcn_s_setprio(1); mm8(0, 1, fB1); __builtin_amdgcn_s_setprio(0);
    bar();
    // ---- p2: A rows [64,128) overwrite fA; stage A(t+2) chunks 0,2
    rdA(aT + 8192);
    if (doA) { stage1(A, pAcur, kA, 0); stage1(A, pAcur, kA, 2); }
    bar(); waitlg0();
    __builtin_amdgcn_s_setprio(1); mm8(2, 1, fB1); __builtin_amdgcn_s_setprio(0);
    bar();
    // ---- p3: no reads; stage A(t+2) chunks 1,3
    if (doA) { stage1(A, pAcur, kA, 1); stage1(A, pAcur, kA, 3); }
    bar();
    __builtin_amdgcn_s_setprio(1); mm8(2, 0, fB0); __builtin_amdgcn_s_setprio(0);
    if (tailmode == 0) waitvm4(); else if (tailmode == 1) waitvm0();
    bar();
  };

  // prologue: A(t0), B(t0), A(t1) staged; A(t1) stays in flight
  stage1(A, pA[0], 0, 0); stage1(A, pA[0], 0, 1);
  stage1(A, pA[0], 0, 2); stage1(A, pA[0], 0, 3);
  stage1(B, pB[0], 0, 0); stage1(B, pB[0], 0, 1);
  stage1(B, pB[0], 0, 2); stage1(B, pB[0], 0, 3);
  stage1(A, pA[1], 64, 0); stage1(A, pA[1], 64, 1);
  stage1(A, pA[1], 64, 2); stage1(A, pA[1], 64, 3);
  waitvm4(); bar();

#pragma unroll 1
  for (int t = 0; t < 30; t += 2) {
    tile4(aT0, bT0, pA[0], pB[1], (t + 1) * 64, true, (t + 2) * 64, true, 0);
    tile4(aT1, bT1, pA[1], pB[0], (t + 2) * 64, true, (t + 3) * 64, true, 0);
  }
  tile4(aT0, bT0, pA[0], pB[1], 31 * 64, true, 0, false, 1);
  tile4(aT1, bT1, pA[1], nullptr, 0, false, 0, false, 2);
}

// C/D layout 32x32 (HW-verified): col=lane&31, row=(reg&3)+8*(reg>>2)+4*hi
__device__ __forceinline__ void store256(h16_t* __restrict__ C,
                                         f32x16 acc[4][2], int bm, int bn)
{
  const int tid = threadIdx.x, wid = tid >> 6, lane = tid & 63;
  const int wr2 = wid >> 2, wcid = wid & 3;
  const int l31 = lane & 31, hi = lane >> 5;
  const int gr0 = bm * 256 + wr2 * 128 + 4 * hi;
  const int gc0 = bn * 256 + wcid * 64 + l31;
#pragma unroll
  for (int am = 0; am < 4; am++)
#pragma unroll
    for (int r = 0; r < 16; r++) {
      const int row = gr0 + am * 32 + (r & 3) + 8 * (r >> 2);
      const long long ro = (long long)row * HDIM;
#pragma unroll
      for (int nj = 0; nj < 2; nj++)
        C[ro + gc0 + nj * 32] = (h16_t)acc[am][nj][r];
    }
}

// XCD-grouped bijective swizzle for 256-block launches (XCD = flat%8):
// XCD c gets logical ids [c*32, c*32+32) => 4 contiguous bm x all bn =>
// A-panels L2-resident per XCD (4MB), B panel streams.
template<int GY>
__device__ __forceinline__ void remap256(int& bn, int& bm, int& z) {
  const int flat = blockIdx.x + 8 * (blockIdx.y + GY * blockIdx.z);
  const int l = (flat & 7) * 32 + (flat >> 3);
  bn = l & 7;
  const int rest = l >> 3;
  bm = rest & (GY - 1);
  z  = rest / GY;
}

// ---------------------------------------------------------------------------
template<int GY>
__global__ __launch_bounds__(512, 2)
void gemm256_b(const h16_t* __restrict__ Ab, const h16_t* __restrict__ Bb,
               h16_t* __restrict__ Cb, long long sAz, long long sBz, long long sCz)
{
  __shared__ __align__(16) h16_t smem[4 * 16384];
  int bn, bm, z;
  remap256<GY>(bn, bm, z);
  const h16_t* A = Ab + (long long)z * sAz + (long long)bm * 256 * HDIM;
  const h16_t* B = Bb + (long long)z * sBz + (long long)bn * 256 * HDIM;
  f32x16 acc[4][2];
  core256(A, B, smem, acc);
  store256(Cb + (long long)z * sCz, acc, bm, bn);
}

// uT GEMM (z<4) + in-place softmax of sc rows (z>=4, 8 rows/block,
// one 2048-wide row per 64-lane wave, 32 f16/lane).
__global__ __launch_bounds__(512, 2)
void gemm256_ut_softmax(const h16_t* __restrict__ Wvow, const h16_t* __restrict__ xb,
                        h16_t* __restrict__ ut, h16_t* __restrict__ sc)
{
  const int tid = threadIdx.x;
  if (blockIdx.z >= 4) {
    const int wid = tid >> 6, lane = tid & 63;
    const long long row = (long long)(blockIdx.z - 4) * 512 +
                          (blockIdx.y * 8 + blockIdx.x) * 8 + wid;
    h16_t* s = sc + row * HDIM;
    h16x8 raw[4];
#pragma unroll
    for (int i = 0; i < 4; i++) raw[i] = ((const h16x8*)s)[i * 64 + lane];
    float v[32];
    float mx = -3.0e38f;
#pragma unroll
    for (int i = 0; i < 32; i++) { v[i] = (float)raw[i >> 3][i & 7]; mx = fmaxf(mx, v[i]); }
#pragma unroll
    for (int off = 32; off; off >>= 1) mx = fmaxf(mx, __shfl_xor(mx, off, 64));
    float sum = 0.f;
#pragma unroll
    for (int i = 0; i < 32; i++) { v[i] = __expf(v[i] - mx); sum += v[i]; }
#pragma unroll
    for (int off = 32; off; off >>= 1) sum += __shfl_xor(sum, off, 64);
    const float inv = 1.0f / sum;
#pragma unroll
    for (int i = 0; i < 4; i++) {
      h16x8 o;
#pragma unroll
      for (int j = 0; j < 8; j++) o[j] = (h16_t)(v[i * 8 + j] * inv);
      ((h16x8*)s)[i * 64 + lane] = o;
    }
    return;
  }
  __shared__ __align__(16) h16_t smem[4 * 16384];
  int bn, bm, z;
  remap256<8>(bn, bm, z);
  const h16_t* A = Wvow + (long long)bm * 256 * HDIM;
  const h16_t* B = xb + (long long)z * (long long)HDIM * HDIM + (long long)bn * 256 * HDIM;
  f32x16 acc[4][2];
  core256(A, B, smem, acc);
  store256(ut + (long long)z * (long long)HDIM * HDIM, acc, bm, bn);
}

// final: out += sum relu(P @ u) . colsum(W2)
__global__ __launch_bounds__(512, 2)
void gemm256_final(const h16_t* __restrict__ P, const h16_t* __restrict__ utb,
                   const float* __restrict__ w2p, float* __restrict__ outp)
{
  __shared__ __align__(16) h16_t smem[4 * 16384];
  int bn, bm, z;
  remap256<8>(bn, bm, z);
  const long long HH = (long long)HDIM * HDIM;
  const h16_t* A = P   + (long long)z * HH + (long long)bm * 256 * HDIM;
  const h16_t* B = utb + (long long)z * HH + (long long)bn * 256 * HDIM;
  f32x16 acc[4][2];
  core256(A, B, smem, acc);

  const int tid = threadIdx.x, wid = tid >> 6, lane = tid & 63;
  const int wcid = wid & 3, l31 = lane & 31;
  const int gc0 = bn * 256 + wcid * 64 + l31;
  float w2j[2];
#pragma unroll
  for (int nj = 0; nj < 2; nj++) {
    const int col = gc0 + nj * 32;
    float s = 0.f;
#pragma unroll
    for (int c = 0; c < 16; c++) s += w2p[c * HDIM + col];
    w2j[nj] = s;
  }
  float s = 0.f;
#pragma unroll
  for (int am = 0; am < 4; am++)
#pragma unroll
    for (int nj = 0; nj < 2; nj++)
#pragma unroll
      for (int r = 0; r < 16; r++) {
        const float vv = acc[am][nj][r];
        s += (vv > 0.f) ? vv * w2j[nj] : 0.f;
      }
#pragma unroll
  for (int off = 32; off; off >>= 1) s += __shfl_down(s, off, 64);
  __shared__ float red[8];
  if (lane == 0) red[wid] = s;
  __syncthreads();
  if (tid == 0) {
    float t = 0.f;
#pragma unroll
    for (int w = 0; w < 8; w++) t += red[w];
    atomicAdd(outp, t);
  }
}

// ---------------------------------------------------------------------------
// mega-prologue: one launch for all converts / transposes / colsum / zero.
__global__ __launch_bounds__(256)
void prologue_kernel(const float* __restrict__ x,  const float* __restrict__ Wq,
                     const float* __restrict__ Wk, const float* __restrict__ Wv,
                     const float* __restrict__ Wo, const float* __restrict__ W1,
                     const float* __restrict__ W2,
                     h16_t* __restrict__ xb,  h16_t* __restrict__ WkT,
                     h16_t* __restrict__ WvT, h16_t* __restrict__ WqT,
                     h16_t* __restrict__ Wob, h16_t* __restrict__ W1b,
                     float* __restrict__ w2p, float* __restrict__ outp)
{
  const int t = threadIdx.x;
  int b = blockIdx.x;
  if (b < 16384) {                       // x: fp32 -> f16, 4/thread
    const long long i = (long long)b * 256 + t;
    const float4 v = ((const float4*)x)[i];
    h16x4 o;
    o[0] = (h16_t)v.x; o[1] = (h16_t)v.y; o[2] = (h16_t)v.z; o[3] = (h16_t)v.w;
    ((h16x4*)xb)[i] = o;
    return;
  }
  b -= 16384;
  if (b < 12288) {                       // Wk,Wv,Wq transposed converts
    const float* src; h16_t* dst;
    if (b < 4096)      { src = Wk; dst = WkT; }
    else if (b < 8192) { src = Wv; dst = WvT; b -= 4096; }
    else               { src = Wq; dst = WqT; b -= 8192; }
    __shared__ float tl[32][33];
    const int bx = (b & 63) * 32, by = (b >> 6) * 32;
    const int xx = t & 31, y0 = t >> 5;
    for (int y = y0; y < 32; y += 8)
      tl[y][xx] = src[(long long)(by + y) * 2048 + bx + xx];
    __syncthreads();
    for (int y = y0; y < 32; y += 8)
      dst[(long long)(bx + y) * 2048 + by + xx] = (h16_t)tl[xx][y];
    return;
  }
  b -= 12288;
  if (b < 8192) {                        // Wo, W1 plain converts
    const float* src = (b < 4096) ? Wo : W1;
    h16_t* dst = (b < 4096) ? Wob : W1b;
    const long long i = (long long)(b & 4095) * 256 + t;
    const float4 v = ((const float4*)src)[i];
    h16x4 o;
    o[0] = (h16_t)v.x; o[1] = (h16_t)v.y; o[2] = (h16_t)v.z; o[3] = (h16_t)v.w;
    ((h16x4*)dst)[i] = o;
    return;
  }
  b -= 8192;
  if (b < 128) {                         // W2 colsum partials (non-atomic)
    const int c = b >> 3;
    const int h = (b & 7) * 256 + t;
    float s = 0.f;
#pragma unroll 4
    for (int d = 0; d < 128; d++) s += W2[(long long)(c * 128 + d) * 2048 + h];
    w2p[c * 2048 + h] = s;
    return;
  }
  b -= 128;
  if (b == 0 && t == 0) outp[0] = 0.f;   // zero the output accumulator
}

// ---------------------------------------------------------------------------
extern "C" void kernel_launch(void* const* d_in, const int* in_sizes, int n_in,
                              void* d_out, int out_size, void* d_ws, size_t ws_size,
                              hipStream_t stream)
{
  const float* x  = (const float*)d_in[0];
  const float* Wq = (const float*)d_in[1];
  const float* Wk = (const float*)d_in[2];
  const float* Wv = (const float*)d_in[3];
  const float* Wo = (const float*)d_in[4];
  const float* W1 = (const float*)d_in[5];
  const float* W2 = (const float*)d_in[6];
  float* out = (float*)d_out;

  const long long HH = (long long)HDIM * HDIM;   // 4,194,304
  const long long XE = (long long)MROWS * HDIM;  // 16,777,216

  // Algebra: score = x (Wq^T Wk) x^T;  h = relu(P x (W1 Wo Wv)^T);
  //          out = sum h.colsum(W2)
  char* p = (char*)d_ws;
  h16_t* xb   = (h16_t*)p; p += XE * 2;
  h16_t* WkT  = (h16_t*)p; p += HH * 2;
  h16_t* WvT  = (h16_t*)p; p += HH * 2;
  h16_t* WqT  = (h16_t*)p; p += HH * 2;
  h16_t* Wob  = (h16_t*)p; p += HH * 2;
  h16_t* WqkT = (h16_t*)p; p += HH * 2;
  h16_t* GT   = (h16_t*)p; p += HH * 2;
  h16_t* W1b  = (h16_t*)p; p += HH * 2;
  h16_t* Wvow = (h16_t*)p; p += HH * 2;
  h16_t* tb   = (h16_t*)p; p += XE * 2;  // t, then uT
  h16_t* sc   = (h16_t*)p; p += XE * 2;  // score -> P in place
  float* w2p  = (float*)p; p += 16 * HDIM * 4;

  const dim3 b256(256), b512(512);

  // 1. mega-prologue: converts, transposes, colsum, zero-out
  prologue_kernel<<<dim3(16384 + 12288 + 8192 + 128 + 1), b256, 0, stream>>>(
      x, Wq, Wk, Wv, Wo, W1, W2, xb, WkT, WvT, WqT, Wob, W1b, w2p, out);

  // 2. batched fold: WqkT = (Wq^T Wk)^T ; GT = (Wo Wv)^T   (128^2 kernel)
  gemm_b<<<dim3(16, 16, 2), b256, 0, stream>>>(WkT, WqT, WqkT, HH, HH, HH);

  // 3. Wvow = W1.G fold (128^2 kernel, 256 balanced blocks)
  gemm_b<<<dim3(16, 16, 1), b256, 0, stream>>>(W1b, GT, Wvow, 0, 0, 0);

  // 4. t = x@Wqk   (256^2 8-phase, 8x32 = 256 blocks, 1/CU)
  gemm256_b<32><<<dim3(8, 32, 1), b512, 0, stream>>>(xb, WqkT, tb, 0, 0, 0);

  // 5. score[b,i,j] = sum_e t[b,i,e]*x[b,j,e]   (256 blocks)
  gemm256_b<8><<<dim3(8, 8, 4), b512, 0, stream>>>(tb, xb, sc, HH, HH, HH);

  // 6. uT[b,e,j] = sum_h Wvow[e,h]*x[b,j,h] (z<4, into tb) + softmax(sc) (z>=4)
  gemm256_ut_softmax<<<dim3(8, 8, 20), b512, 0, stream>>>(Wvow, xb, tb, sc);

  // 7. out += sum relu(P @ u) . w2
  gemm256_final<<<dim3(8, 8, 4), b512, 0, stream>>>(sc, tb, w2p, out);
}

// Round 4
// 532.359 us; speedup vs baseline: 2.2095x; 1.0350x over previous
//
#include <hip/hip_runtime.h>
#include <hip/hip_bf16.h>
#include <stdint.h>

typedef _Float16 h16_t;
typedef __attribute__((ext_vector_type(8))) _Float16 h16x8;
typedef __attribute__((ext_vector_type(4))) _Float16 h16x4;
typedef __attribute__((ext_vector_type(16))) float f32x16;

static constexpr int HDIM  = 2048;
static constexpr int MROWS = 8192;                   // 4 batches x 2048

// ---------------------------------------------------------------------------
__device__ __forceinline__ void gload_lds16(const h16_t* g, h16_t* l) {
  __builtin_amdgcn_global_load_lds(
      (const __attribute__((address_space(1))) void*)g,
      (__attribute__((address_space(3))) void*)l, 16, 0, 0);
}

__device__ __forceinline__ uint32_t ldsaddr(const void* p) {
  return (uint32_t)(uintptr_t)(const __attribute__((address_space(3))) void*)p;
}

__device__ __forceinline__ h16x8 dsread(uint32_t off) {
  h16x8 r;
  asm volatile("ds_read_b128 %0, %1" : "=v"(r) : "v"(off));
  return r;
}

__device__ __forceinline__ void sbar()  { __builtin_amdgcn_sched_barrier(0); }
__device__ __forceinline__ void bar()   { sbar(); __builtin_amdgcn_s_barrier(); sbar(); }
__device__ __forceinline__ void waitlg0(){ asm volatile("s_waitcnt lgkmcnt(0)" ::: "memory"); sbar(); }
__device__ __forceinline__ void waitvm4(){ asm volatile("s_waitcnt vmcnt(4)" ::: "memory"); sbar(); }
__device__ __forceinline__ void waitvm0(){ asm volatile("s_waitcnt vmcnt(0)" ::: "memory"); sbar(); }

// ===========================================================================
// OLD 128x128 core (m97-structure) — kept for the small weight-fold GEMMs
// (launch packing: 512/256 blocks of 128^2 fill all CUs; 256^2 would idle
// half the chip on a 2048^2 output).
// ===========================================================================
__device__ __forceinline__ void gemm_core(const h16_t* __restrict__ A,
                                          const h16_t* __restrict__ B,
                                          f32x16 acc[2][2],
                                          h16_t* sA, h16_t* sB) {
  const int tid  = threadIdx.x;
  const int wid  = tid >> 6;
  const int lane = tid & 63;
  const int wr  = (wid >> 1) << 6;
  const int wc  = (wid & 1) << 6;
  const int l31 = lane & 31;
  const int hi  = lane >> 5;
  const int sx  = lane & 7;

#pragma unroll
  for (int i = 0; i < 2; i++)
#pragma unroll
    for (int j = 0; j < 2; j++)
#pragma unroll
      for (int r = 0; r < 16; r++) acc[i][j][r] = 0.0f;

  for (int k0 = 0; k0 < 2048; k0 += 64) {
    __syncthreads();
#pragma unroll
    for (int rnd = 0; rnd < 4; rnd++) {
      const int cid  = rnd * 256 + tid;
      const int row  = cid >> 3;
      const int koct = (cid & 7) ^ (row & 7);
      const long long goff = (long long)row * 2048 + k0 + koct * 8;
      gload_lds16(A + goff, sA + (rnd * 256 + wid * 64) * 8);
      gload_lds16(B + goff, sB + (rnd * 256 + wid * 64) * 8);
    }
    __syncthreads();

#pragma unroll
    for (int ko = 0; ko < 4; ko++) {
      const int po = (2 * ko + hi) ^ sx;
      h16x8 fa[2], fb[2];
#pragma unroll
      for (int i = 0; i < 2; i++)
        fa[i] = *(const h16x8*)(sA + (wr + i * 32 + l31) * 64 + po * 8);
#pragma unroll
      for (int j = 0; j < 2; j++)
        fb[j] = *(const h16x8*)(sB + (wc + j * 32 + l31) * 64 + po * 8);
#pragma unroll
      for (int i = 0; i < 2; i++)
#pragma unroll
        for (int j = 0; j < 2; j++)
          acc[i][j] = __builtin_amdgcn_mfma_f32_32x32x16_f16(
              fa[i], fb[j], acc[i][j], 0, 0, 0);
    }
  }
}

__device__ __forceinline__ void store_c(h16_t* __restrict__ C,
                                        f32x16 acc[2][2], int bm, int bn) {
  const int tid  = threadIdx.x;
  const int wid  = tid >> 6;
  const int lane = tid & 63;
  const int wr = (wid >> 1) << 6, wc = (wid & 1) << 6;
  const int l31 = lane & 31, hi = lane >> 5;
  const int gr = bm * 128 + wr + 4 * hi;
  const int gc = bn * 128 + wc + l31;
#pragma unroll
  for (int i = 0; i < 2; i++)
#pragma unroll
    for (int r = 0; r < 16; r++) {
      const int row = gr + i * 32 + (r & 3) + 8 * (r >> 2);
      const long long ro = (long long)row * 2048;
#pragma unroll
      for (int j = 0; j < 2; j++)
        C[ro + gc + j * 32] = (h16_t)acc[i][j][r];
    }
}

__global__ __launch_bounds__(256)
void gemm_b(const h16_t* __restrict__ Ab, const h16_t* __restrict__ Bb,
            h16_t* __restrict__ Cb, long long sAz, long long sBz, long long sCz)
{
  __shared__ __align__(16) h16_t sA[128 * 64];
  __shared__ __align__(16) h16_t sB[128 * 64];
  const int bn = blockIdx.x, bm = blockIdx.y, z = blockIdx.z;
  const h16_t* A = Ab + (long long)z * sAz + (long long)bm * 128 * 2048;
  const h16_t* B = Bb + (long long)z * sBz + (long long)bn * 128 * 2048;
  f32x16 acc[2][2];
  gemm_core(A, B, acc, sA, sB);
  store_c(Cb + (long long)z * sCz, acc, bm, bn);
}

// ===========================================================================
// 256x256 8-phase core, v2 (register-lean) — unchanged from the passing
// round-2 version. fA[2][4] reused (p0 reads rows [0,64), p2 overwrites with
// [64,128) after last use); counted vmcnt(4) once per K-tile; raw s_barrier;
// lgkmcnt(0)+sched_barrier before MFMA; s_setprio around MFMA clusters.
// ===========================================================================
__device__ __forceinline__ void core256(const h16_t* __restrict__ A,
                                        const h16_t* __restrict__ B,
                                        h16_t* smem, f32x16 acc[4][2])
{
  const int tid  = threadIdx.x;
  const int wid  = tid >> 6, lane = tid & 63;
  const int wr2  = wid >> 2, wcid = wid & 3;
  const int l31  = lane & 31, hi = lane >> 5, sx = lane & 7;

  h16_t* pA[2] = { smem,          smem + 32768 };   // 32KB panels
  h16_t* pB[2] = { smem + 16384,  smem + 49152 };

  uint32_t poB[4];
#pragma unroll
  for (int ks = 0; ks < 4; ks++) poB[ks] = (uint32_t)((((2 * ks + hi) ^ sx) << 4));
  const uint32_t lrow = (uint32_t)(l31 * 128);
  const uint32_t aT0 = ldsaddr(pA[0]) + (uint32_t)(wr2 * 16384) + lrow;
  const uint32_t aT1 = ldsaddr(pA[1]) + (uint32_t)(wr2 * 16384) + lrow;
  const uint32_t bT0 = ldsaddr(pB[0]) + (uint32_t)(wcid * 8192) + lrow;
  const uint32_t bT1 = ldsaddr(pB[1]) + (uint32_t)(wcid * 8192) + lrow;

  const int srow = tid >> 3;
  const long long stOff = (long long)srow * HDIM + (long long)(((tid & 7) ^ (srow & 7)) * 8);
  const int dOff = tid * 8;

  auto stage1 = [&](const h16_t* M, h16_t* panel, int k0, int ci) {
    gload_lds16(M + stOff + k0 + (long long)ci * (64 * HDIM),
                panel + ci * 4096 + dOff);
  };

#pragma unroll
  for (int i = 0; i < 4; i++)
#pragma unroll
    for (int j = 0; j < 2; j++)
#pragma unroll
      for (int r = 0; r < 16; r++) acc[i][j][r] = 0.0f;

  h16x8 fA[2][4], fB0[4], fB1[4];

  auto rdA = [&](uint32_t base) {            // 8 reads -> fA (overwrites)
#pragma unroll
    for (int mi = 0; mi < 2; mi++)
#pragma unroll
      for (int ks = 0; ks < 4; ks++)
        fA[mi][ks] = dsread(base + (uint32_t)(mi * 4096) + poB[ks]);
  };
  auto rdB = [&](h16x8 (&fb)[4], uint32_t base) {  // 4 reads
#pragma unroll
    for (int ks = 0; ks < 4; ks++) fb[ks] = dsread(base + poB[ks]);
  };
  auto mm8 = [&](int am0, int nj, h16x8 (&fb)[4]) {
#pragma unroll
    for (int ks = 0; ks < 4; ks++)
#pragma unroll
      for (int mi = 0; mi < 2; mi++)
        acc[am0 + mi][nj] = __builtin_amdgcn_mfma_f32_32x32x16_f16(
            fA[mi][ks], fb[ks], acc[am0 + mi][nj], 0, 0, 0);
  };

  // tailmode: 0 = vmcnt(4)+bar, 1 = vmcnt(0)+bar, 2 = bar only
  auto tile4 = [&](uint32_t aT, uint32_t bT, h16_t* pAcur,
                   h16_t* stB, int kB, bool doB,
                   int kA, bool doA, int tailmode) {
    // ---- p0: A rows [0,64), B cols [0,32); stage B(t+1) chunks 0,1
    rdA(aT);
    rdB(fB0, bT);
    if (doB) { stage1(B, stB, kB, 0); stage1(B, stB, kB, 1); }
    bar(); waitlg0();
    __builtin_amdgcn_s_setprio(1); mm8(0, 0, fB0); __builtin_amdgcn_s_setprio(0);
    bar();
    // ---- p1: B cols [32,64); stage B(t+1) chunks 2,3
    rdB(fB1, bT + 4096);
    if (doB) { stage1(B, stB, kB, 2); stage1(B, stB, kB, 3); }
    bar(); waitlg0();
    __builtin_amdgcn_s_setprio(1); mm8(0, 1, fB1); __builtin_amdgcn_s_setprio(0);
    bar();
    // ---- p2: A rows [64,128) overwrite fA; stage A(t+2) chunks 0,2
    rdA(aT + 8192);
    if (doA) { stage1(A, pAcur, kA, 0); stage1(A, pAcur, kA, 2); }
    bar(); waitlg0();
    __builtin_amdgcn_s_setprio(1); mm8(2, 1, fB1); __builtin_amdgcn_s_setprio(0);
    bar();
    // ---- p3: no reads; stage A(t+2) chunks 1,3
    if (doA) { stage1(A, pAcur, kA, 1); stage1(A, pAcur, kA, 3); }
    bar();
    __builtin_amdgcn_s_setprio(1); mm8(2, 0, fB0); __builtin_amdgcn_s_setprio(0);
    if (tailmode == 0) waitvm4(); else if (tailmode == 1) waitvm0();
    bar();
  };

  // prologue: A(t0), B(t0), A(t1) staged; A(t1) stays in flight
  stage1(A, pA[0], 0, 0); stage1(A, pA[0], 0, 1);
  stage1(A, pA[0], 0, 2); stage1(A, pA[0], 0, 3);
  stage1(B, pB[0], 0, 0); stage1(B, pB[0], 0, 1);
  stage1(B, pB[0], 0, 2); stage1(B, pB[0], 0, 3);
  stage1(A, pA[1], 64, 0); stage1(A, pA[1], 64, 1);
  stage1(A, pA[1], 64, 2); stage1(A, pA[1], 64, 3);
  waitvm4(); bar();

#pragma unroll 1
  for (int t = 0; t < 30; t += 2) {
    tile4(aT0, bT0, pA[0], pB[1], (t + 1) * 64, true, (t + 2) * 64, true, 0);
    tile4(aT1, bT1, pA[1], pB[0], (t + 2) * 64, true, (t + 3) * 64, true, 0);
  }
  tile4(aT0, bT0, pA[0], pB[1], 31 * 64, true, 0, false, 1);
  tile4(aT1, bT1, pA[1], nullptr, 0, false, 0, false, 2);
}

// C/D layout 32x32 (HW-verified): col=lane&31, row=(reg&3)+8*(reg>>2)+4*hi
__device__ __forceinline__ void store256(h16_t* __restrict__ C,
                                         f32x16 acc[4][2], int bm, int bn)
{
  const int tid = threadIdx.x, wid = tid >> 6, lane = tid & 63;
  const int wr2 = wid >> 2, wcid = wid & 3;
  const int l31 = lane & 31, hi = lane >> 5;
  const int gr0 = bm * 256 + wr2 * 128 + 4 * hi;
  const int gc0 = bn * 256 + wcid * 64 + l31;
#pragma unroll
  for (int am = 0; am < 4; am++)
#pragma unroll
    for (int r = 0; r < 16; r++) {
      const int row = gr0 + am * 32 + (r & 3) + 8 * (r >> 2);
      const long long ro = (long long)row * HDIM;
#pragma unroll
      for (int nj = 0; nj < 2; nj++)
        C[ro + gc0 + nj * 32] = (h16_t)acc[am][nj][r];
    }
}

// XCD-grouped bijective swizzle for 256-block launches (XCD = flat%8):
// XCD c gets logical ids [c*32, c*32+32) => 4 contiguous bm x all bn =>
// A-panels L2-resident per XCD (4MB), B panel streams.
template<int GY>
__device__ __forceinline__ void remap256(int& bn, int& bm, int& z) {
  const int flat = blockIdx.x + 8 * (blockIdx.y + GY * blockIdx.z);
  const int l = (flat & 7) * 32 + (flat >> 3);
  bn = l & 7;
  const int rest = l >> 3;
  bm = rest & (GY - 1);
  z  = rest / GY;
}

// ---------------------------------------------------------------------------
template<int GY>
__global__ __launch_bounds__(512, 2)
void gemm256_b(const h16_t* __restrict__ Ab, const h16_t* __restrict__ Bb,
               h16_t* __restrict__ Cb, long long sAz, long long sBz, long long sCz)
{
  __shared__ __align__(16) h16_t smem[4 * 16384];
  int bn, bm, z;
  remap256<GY>(bn, bm, z);
  const h16_t* A = Ab + (long long)z * sAz + (long long)bm * 256 * HDIM;
  const h16_t* B = Bb + (long long)z * sBz + (long long)bn * 256 * HDIM;
  f32x16 acc[4][2];
  core256(A, B, smem, acc);
  store256(Cb + (long long)z * sCz, acc, bm, bn);
}

// uT GEMM (z<4) + in-place softmax of sc rows (z>=4, 8 rows/block,
// one 2048-wide row per 64-lane wave, 32 f16/lane).
__global__ __launch_bounds__(512, 2)
void gemm256_ut_softmax(const h16_t* __restrict__ Wvow, const h16_t* __restrict__ xb,
                        h16_t* __restrict__ ut, h16_t* __restrict__ sc)
{
  const int tid = threadIdx.x;
  if (blockIdx.z >= 4) {
    const int wid = tid >> 6, lane = tid & 63;
    const long long row = (long long)(blockIdx.z - 4) * 512 +
                          (blockIdx.y * 8 + blockIdx.x) * 8 + wid;
    h16_t* s = sc + row * HDIM;
    h16x8 raw[4];
#pragma unroll
    for (int i = 0; i < 4; i++) raw[i] = ((const h16x8*)s)[i * 64 + lane];
    float v[32];
    float mx = -3.0e38f;
#pragma unroll
    for (int i = 0; i < 32; i++) { v[i] = (float)raw[i >> 3][i & 7]; mx = fmaxf(mx, v[i]); }
#pragma unroll
    for (int off = 32; off; off >>= 1) mx = fmaxf(mx, __shfl_xor(mx, off, 64));
    float sum = 0.f;
#pragma unroll
    for (int i = 0; i < 32; i++) { v[i] = __expf(v[i] - mx); sum += v[i]; }
#pragma unroll
    for (int off = 32; off; off >>= 1) sum += __shfl_xor(sum, off, 64);
    const float inv = 1.0f / sum;
#pragma unroll
    for (int i = 0; i < 4; i++) {
      h16x8 o;
#pragma unroll
      for (int j = 0; j < 8; j++) o[j] = (h16_t)(v[i * 8 + j] * inv);
      ((h16x8*)s)[i * 64 + lane] = o;
    }
    return;
  }
  __shared__ __align__(16) h16_t smem[4 * 16384];
  int bn, bm, z;
  remap256<8>(bn, bm, z);
  const h16_t* A = Wvow + (long long)bm * 256 * HDIM;
  const h16_t* B = xb + (long long)z * (long long)HDIM * HDIM + (long long)bn * 256 * HDIM;
  f32x16 acc[4][2];
  core256(A, B, smem, acc);
  store256(ut + (long long)z * (long long)HDIM * HDIM, acc, bm, bn);
}

// final: out += sum relu(P @ u) . colsum(W2)  (32 colsum partials now)
__global__ __launch_bounds__(512, 2)
void gemm256_final(const h16_t* __restrict__ P, const h16_t* __restrict__ utb,
                   const float* __restrict__ w2p, float* __restrict__ outp)
{
  __shared__ __align__(16) h16_t smem[4 * 16384];
  int bn, bm, z;
  remap256<8>(bn, bm, z);
  const long long HH = (long long)HDIM * HDIM;
  const h16_t* A = P   + (long long)z * HH + (long long)bm * 256 * HDIM;
  const h16_t* B = utb + (long long)z * HH + (long long)bn * 256 * HDIM;
  f32x16 acc[4][2];
  core256(A, B, smem, acc);

  const int tid = threadIdx.x, wid = tid >> 6, lane = tid & 63;
  const int wcid = wid & 3, l31 = lane & 31;
  const int gc0 = bn * 256 + wcid * 64 + l31;
  float w2j[2];
#pragma unroll
  for (int nj = 0; nj < 2; nj++) {
    const int col = gc0 + nj * 32;
    float s = 0.f;
#pragma unroll
    for (int c = 0; c < 32; c++) s += w2p[c * HDIM + col];
    w2j[nj] = s;
  }
  float s = 0.f;
#pragma unroll
  for (int am = 0; am < 4; am++)
#pragma unroll
    for (int nj = 0; nj < 2; nj++)
#pragma unroll
      for (int r = 0; r < 16; r++) {
        const float vv = acc[am][nj][r];
        s += (vv > 0.f) ? vv * w2j[nj] : 0.f;
      }
#pragma unroll
  for (int off = 32; off; off >>= 1) s += __shfl_down(s, off, 64);
  __shared__ float red[8];
  if (lane == 0) red[wid] = s;
  __syncthreads();
  if (tid == 0) {
    float t = 0.f;
#pragma unroll
    for (int w = 0; w < 8; w++) t += red[w];
    atomicAdd(outp, t);
  }
}

// ---------------------------------------------------------------------------
// mega-prologue v2: vectorized transpose (64x64 f32 LDS tile, float4 loads,
// h16x8 stores — was scalar 4B/2B, the 22%-of-HBM bottleneck), 2x colsum
// parallelism. Segments by blockIdx.x.
__global__ __launch_bounds__(256)
void prologue_kernel(const float* __restrict__ x,  const float* __restrict__ Wq,
                     const float* __restrict__ Wk, const float* __restrict__ Wv,
                     const float* __restrict__ Wo, const float* __restrict__ W1,
                     const float* __restrict__ W2,
                     h16_t* __restrict__ xb,  h16_t* __restrict__ WkT,
                     h16_t* __restrict__ WvT, h16_t* __restrict__ WqT,
                     h16_t* __restrict__ Wob, h16_t* __restrict__ W1b,
                     float* __restrict__ w2p, float* __restrict__ outp)
{
  const int t = threadIdx.x;
  int b = blockIdx.x;
  if (b < 16384) {                       // x: fp32 -> f16, 4/thread
    const long long i = (long long)b * 256 + t;
    const float4 v = ((const float4*)x)[i];
    h16x4 o;
    o[0] = (h16_t)v.x; o[1] = (h16_t)v.y; o[2] = (h16_t)v.z; o[3] = (h16_t)v.w;
    ((h16x4*)xb)[i] = o;
    return;
  }
  b -= 16384;
  if (b < 3072) {                        // Wk,Wv,Wq transposed converts, 64x64
    const float* src; h16_t* dst;
    const int w = b >> 10, b10 = b & 1023;
    if (w == 0)      { src = Wk; dst = WkT; }
    else if (w == 1) { src = Wv; dst = WvT; }
    else             { src = Wq; dst = WqT; }
    __shared__ float tl[64][65];
    const int bx = (b10 & 31) * 64, by = (b10 >> 5) * 64;
#pragma unroll
    for (int i = 0; i < 4; i++) {        // float4 loads: 256B/row contiguous
      const int idx = i * 256 + t;
      const int r = idx >> 4, c4 = idx & 15;
      const float4 v = *(const float4*)(src + (long long)(by + r) * 2048 + bx + c4 * 4);
      tl[r][c4 * 4 + 0] = v.x; tl[r][c4 * 4 + 1] = v.y;
      tl[r][c4 * 4 + 2] = v.z; tl[r][c4 * 4 + 3] = v.w;
    }
    __syncthreads();
#pragma unroll
    for (int i = 0; i < 2; i++) {        // h16x8 stores: 128B contiguous
      const int idx = i * 256 + t;
      const int c = idx >> 3, r8 = (idx & 7) * 8;
      h16x8 o;
#pragma unroll
      for (int j = 0; j < 8; j++) o[j] = (h16_t)tl[r8 + j][c];
      *(h16x8*)(dst + (long long)(bx + c) * 2048 + by + r8) = o;
    }
    return;
  }
  b -= 3072;
  if (b < 8192) {                        // Wo, W1 plain converts
    const float* src = (b < 4096) ? Wo : W1;
    h16_t* dst = (b < 4096) ? Wob : W1b;
    const long long i = (long long)(b & 4095) * 256 + t;
    const float4 v = ((const float4*)src)[i];
    h16x4 o;
    o[0] = (h16_t)v.x; o[1] = (h16_t)v.y; o[2] = (h16_t)v.z; o[3] = (h16_t)v.w;
    ((h16x4*)dst)[i] = o;
    return;
  }
  b -= 8192;
  if (b < 256) {                         // W2 colsum partials (32 x 64 rows)
    const int c = b >> 3;
    const int h = (b & 7) * 256 + t;
    float s = 0.f;
#pragma unroll 4
    for (int d = 0; d < 64; d++) s += W2[(long long)(c * 64 + d) * 2048 + h];
    w2p[c * 2048 + h] = s;
    return;
  }
  b -= 256;
  if (b == 0 && t == 0) outp[0] = 0.f;   // zero the output accumulator
}

// ---------------------------------------------------------------------------
extern "C" void kernel_launch(void* const* d_in, const int* in_sizes, int n_in,
                              void* d_out, int out_size, void* d_ws, size_t ws_size,
                              hipStream_t stream)
{
  const float* x  = (const float*)d_in[0];
  const float* Wq = (const float*)d_in[1];
  const float* Wk = (const float*)d_in[2];
  const float* Wv = (const float*)d_in[3];
  const float* Wo = (const float*)d_in[4];
  const float* W1 = (const float*)d_in[5];
  const float* W2 = (const float*)d_in[6];
  float* out = (float*)d_out;

  const long long HH = (long long)HDIM * HDIM;   // 4,194,304
  const long long XE = (long long)MROWS * HDIM;  // 16,777,216

  // Algebra: score = x (Wq^T Wk) x^T;  h = relu(P x (W1 Wo Wv)^T);
  //          out = sum h.colsum(W2)
  char* p = (char*)d_ws;
  h16_t* xb   = (h16_t*)p; p += XE * 2;
  h16_t* WkT  = (h16_t*)p; p += HH * 2;
  h16_t* WvT  = (h16_t*)p; p += HH * 2;
  h16_t* WqT  = (h16_t*)p; p += HH * 2;
  h16_t* Wob  = (h16_t*)p; p += HH * 2;
  h16_t* WqkT = (h16_t*)p; p += HH * 2;
  h16_t* GT   = (h16_t*)p; p += HH * 2;
  h16_t* W1b  = (h16_t*)p; p += HH * 2;
  h16_t* Wvow = (h16_t*)p; p += HH * 2;
  h16_t* tb   = (h16_t*)p; p += XE * 2;  // t, then uT
  h16_t* sc   = (h16_t*)p; p += XE * 2;  // score -> P in place
  float* w2p  = (float*)p; p += 32 * HDIM * 4;

  const dim3 b256(256), b512(512);

  // 1. mega-prologue: converts, transposes, colsum, zero-out
  prologue_kernel<<<dim3(16384 + 3072 + 8192 + 256 + 1), b256, 0, stream>>>(
      x, Wq, Wk, Wv, Wo, W1, W2, xb, WkT, WvT, WqT, Wob, W1b, w2p, out);

  // 2. batched fold: WqkT = (Wq^T Wk)^T ; GT = (Wo Wv)^T   (128^2 kernel)
  gemm_b<<<dim3(16, 16, 2), b256, 0, stream>>>(WkT, WqT, WqkT, HH, HH, HH);

  // 3. Wvow = W1.G fold (128^2 kernel, 256 balanced blocks)
  gemm_b<<<dim3(16, 16, 1), b256, 0, stream>>>(W1b, GT, Wvow, 0, 0, 0);

  // 4. t = x@Wqk   (256^2 8-phase, 8x32 = 256 blocks, 1/CU)
  gemm256_b<32><<<dim3(8, 32, 1), b512, 0, stream>>>(xb, WqkT, tb, 0, 0, 0);

  // 5. score[b,i,j] = sum_e t[b,i,e]*x[b,j,e]   (256 blocks)
  gemm256_b<8><<<dim3(8, 8, 4), b512, 0, stream>>>(tb, xb, sc, HH, HH, HH);

  // 6. uT[b,e,j] = sum_h Wvow[e,h]*x[b,j,h] (z<4, into tb) + softmax(sc) (z>=4)
  gemm256_ut_softmax<<<dim3(8, 8, 20), b512, 0, stream>>>(Wvow, xb, tb, sc);

  // 7. out += sum relu(P @ u) . w2
  gemm256_final<<<dim3(8, 8, 4), b512, 0, stream>>>(sc, tb, w2p, out);
}

// Round 5
// 527.064 us; speedup vs baseline: 2.2317x; 1.0100x over previous
//
#include <hip/hip_runtime.h>
#include <hip/hip_bf16.h>
#include <stdint.h>

typedef _Float16 h16_t;
typedef __attribute__((ext_vector_type(8))) _Float16 h16x8;
typedef __attribute__((ext_vector_type(4))) _Float16 h16x4;
typedef __attribute__((ext_vector_type(16))) float f32x16;

static constexpr int HDIM  = 2048;
static constexpr int MROWS = 8192;                   // 4 batches x 2048

// ---------------------------------------------------------------------------
__device__ __forceinline__ void gload_lds16(const h16_t* g, h16_t* l) {
  __builtin_amdgcn_global_load_lds(
      (const __attribute__((address_space(1))) void*)g,
      (__attribute__((address_space(3))) void*)l, 16, 0, 0);
}

__device__ __forceinline__ uint32_t ldsaddr(const void* p) {
  return (uint32_t)(uintptr_t)(const __attribute__((address_space(3))) void*)p;
}

__device__ __forceinline__ h16x8 dsread(uint32_t off) {
  h16x8 r;
  asm volatile("ds_read_b128 %0, %1" : "=v"(r) : "v"(off));
  return r;
}

// de-pinned barriers (R4): volatile/intrinsic side-effect order already keeps
// asm ds_read / global_load_lds / s_barrier in program order; the ONLY
// register-only hazard is MFMA hoisting above lgkmcnt (rule #18) -> keep that
// single sched_barrier. m141: blanket sched_barrier(0) pinning regresses.
__device__ __forceinline__ void bar()    { __builtin_amdgcn_s_barrier(); }
__device__ __forceinline__ void waitlg0(){ asm volatile("s_waitcnt lgkmcnt(0)" ::: "memory");
                                           __builtin_amdgcn_sched_barrier(0); }
__device__ __forceinline__ void waitvm4(){ asm volatile("s_waitcnt vmcnt(4)" ::: "memory"); }
__device__ __forceinline__ void waitvm0(){ asm volatile("s_waitcnt vmcnt(0)" ::: "memory"); }

// ===========================================================================
// OLD 128x128 core (m97-structure) — kept for the small weight-fold GEMMs
// (launch packing: 512/256 blocks of 128^2 fill all CUs).
// ===========================================================================
__device__ __forceinline__ void gemm_core(const h16_t* __restrict__ A,
                                          const h16_t* __restrict__ B,
                                          f32x16 acc[2][2],
                                          h16_t* sA, h16_t* sB) {
  const int tid  = threadIdx.x;
  const int wid  = tid >> 6;
  const int lane = tid & 63;
  const int wr  = (wid >> 1) << 6;
  const int wc  = (wid & 1) << 6;
  const int l31 = lane & 31;
  const int hi  = lane >> 5;
  const int sx  = lane & 7;

#pragma unroll
  for (int i = 0; i < 2; i++)
#pragma unroll
    for (int j = 0; j < 2; j++)
#pragma unroll
      for (int r = 0; r < 16; r++) acc[i][j][r] = 0.0f;

  for (int k0 = 0; k0 < 2048; k0 += 64) {
    __syncthreads();
#pragma unroll
    for (int rnd = 0; rnd < 4; rnd++) {
      const int cid  = rnd * 256 + tid;
      const int row  = cid >> 3;
      const int koct = (cid & 7) ^ (row & 7);
      const long long goff = (long long)row * 2048 + k0 + koct * 8;
      gload_lds16(A + goff, sA + (rnd * 256 + wid * 64) * 8);
      gload_lds16(B + goff, sB + (rnd * 256 + wid * 64) * 8);
    }
    __syncthreads();

#pragma unroll
    for (int ko = 0; ko < 4; ko++) {
      const int po = (2 * ko + hi) ^ sx;
      h16x8 fa[2], fb[2];
#pragma unroll
      for (int i = 0; i < 2; i++)
        fa[i] = *(const h16x8*)(sA + (wr + i * 32 + l31) * 64 + po * 8);
#pragma unroll
      for (int j = 0; j < 2; j++)
        fb[j] = *(const h16x8*)(sB + (wc + j * 32 + l31) * 64 + po * 8);
#pragma unroll
      for (int i = 0; i < 2; i++)
#pragma unroll
        for (int j = 0; j < 2; j++)
          acc[i][j] = __builtin_amdgcn_mfma_f32_32x32x16_f16(
              fa[i], fb[j], acc[i][j], 0, 0, 0);
    }
  }
}

__device__ __forceinline__ void store_c(h16_t* __restrict__ C,
                                        f32x16 acc[2][2], int bm, int bn) {
  const int tid  = threadIdx.x;
  const int wid  = tid >> 6;
  const int lane = tid & 63;
  const int wr = (wid >> 1) << 6, wc = (wid & 1) << 6;
  const int l31 = lane & 31, hi = lane >> 5;
  const int gr = bm * 128 + wr + 4 * hi;
  const int gc = bn * 128 + wc + l31;
#pragma unroll
  for (int i = 0; i < 2; i++)
#pragma unroll
    for (int r = 0; r < 16; r++) {
      const int row = gr + i * 32 + (r & 3) + 8 * (r >> 2);
      const long long ro = (long long)row * 2048;
#pragma unroll
      for (int j = 0; j < 2; j++)
        C[ro + gc + j * 32] = (h16_t)acc[i][j][r];
    }
}

__global__ __launch_bounds__(256)
void gemm_b(const h16_t* __restrict__ Ab, const h16_t* __restrict__ Bb,
            h16_t* __restrict__ Cb, long long sAz, long long sBz, long long sCz)
{
  __shared__ __align__(16) h16_t sA[128 * 64];
  __shared__ __align__(16) h16_t sB[128 * 64];
  const int bn = blockIdx.x, bm = blockIdx.y, z = blockIdx.z;
  const h16_t* A = Ab + (long long)z * sAz + (long long)bm * 128 * 2048;
  const h16_t* B = Bb + (long long)z * sBz + (long long)bn * 128 * 2048;
  f32x16 acc[2][2];
  gemm_core(A, B, acc, sA, sB);
  store_c(Cb + (long long)z * sCz, acc, bm, bn);
}

// ===========================================================================
// 256x256 8-phase core, v3: register-lean (R2) + de-pinned barriers (R4).
// fA[2][4] reused (p0 reads rows [0,64), p2 overwrites with [64,128) after
// last use in p1); counted vmcnt(4) once per K-tile (never 0 in main loop);
// raw s_barrier; lgkmcnt(0)+sched_barrier before MFMA; s_setprio around
// each 8-MFMA cluster. LDS-overwrite safety: A(t+2) chunks {0,2} staged in
// p2 (that half drained by every wave's lgkmcnt before the p0-end barrier),
// {1,3} in p3 (drained before p2-end barrier).
// ===========================================================================
__device__ __forceinline__ void core256(const h16_t* __restrict__ A,
                                        const h16_t* __restrict__ B,
                                        h16_t* smem, f32x16 acc[4][2])
{
  const int tid  = threadIdx.x;
  const int wid  = tid >> 6, lane = tid & 63;
  const int wr2  = wid >> 2, wcid = wid & 3;
  const int l31  = lane & 31, hi = lane >> 5, sx = lane & 7;

  h16_t* pA[2] = { smem,          smem + 32768 };   // 32KB panels
  h16_t* pB[2] = { smem + 16384,  smem + 49152 };

  uint32_t poB[4];
#pragma unroll
  for (int ks = 0; ks < 4; ks++) poB[ks] = (uint32_t)((((2 * ks + hi) ^ sx) << 4));
  const uint32_t lrow = (uint32_t)(l31 * 128);
  const uint32_t aT0 = ldsaddr(pA[0]) + (uint32_t)(wr2 * 16384) + lrow;
  const uint32_t aT1 = ldsaddr(pA[1]) + (uint32_t)(wr2 * 16384) + lrow;
  const uint32_t bT0 = ldsaddr(pB[0]) + (uint32_t)(wcid * 8192) + lrow;
  const uint32_t bT1 = ldsaddr(pB[1]) + (uint32_t)(wcid * 8192) + lrow;

  const int srow = tid >> 3;
  const long long stOff = (long long)srow * HDIM + (long long)(((tid & 7) ^ (srow & 7)) * 8);
  const int dOff = tid * 8;

  auto stage1 = [&](const h16_t* M, h16_t* panel, int k0, int ci) {
    gload_lds16(M + stOff + k0 + (long long)ci * (64 * HDIM),
                panel + ci * 4096 + dOff);
  };

#pragma unroll
  for (int i = 0; i < 4; i++)
#pragma unroll
    for (int j = 0; j < 2; j++)
#pragma unroll
      for (int r = 0; r < 16; r++) acc[i][j][r] = 0.0f;

  h16x8 fA[2][4], fB0[4], fB1[4];

  auto rdA = [&](uint32_t base) {            // 8 reads -> fA (overwrites)
#pragma unroll
    for (int mi = 0; mi < 2; mi++)
#pragma unroll
      for (int ks = 0; ks < 4; ks++)
        fA[mi][ks] = dsread(base + (uint32_t)(mi * 4096) + poB[ks]);
  };
  auto rdB = [&](h16x8 (&fb)[4], uint32_t base) {  // 4 reads
#pragma unroll
    for (int ks = 0; ks < 4; ks++) fb[ks] = dsread(base + poB[ks]);
  };
  auto mm8 = [&](int am0, int nj, h16x8 (&fb)[4]) {
#pragma unroll
    for (int ks = 0; ks < 4; ks++)
#pragma unroll
      for (int mi = 0; mi < 2; mi++)
        acc[am0 + mi][nj] = __builtin_amdgcn_mfma_f32_32x32x16_f16(
            fA[mi][ks], fb[ks], acc[am0 + mi][nj], 0, 0, 0);
  };

  // tailmode: 0 = vmcnt(4)+bar, 1 = vmcnt(0)+bar, 2 = bar only
  auto tile4 = [&](uint32_t aT, uint32_t bT, h16_t* pAcur,
                   h16_t* stB, int kB, bool doB,
                   int kA, bool doA, int tailmode) {
    // ---- p0: A rows [0,64), B cols [0,32); stage B(t+1) chunks 0,1
    rdA(aT);
    rdB(fB0, bT);
    if (doB) { stage1(B, stB, kB, 0); stage1(B, stB, kB, 1); }
    bar(); waitlg0();
    __builtin_amdgcn_s_setprio(1); mm8(0, 0, fB0); __builtin_amdgcn_s_setprio(0);
    bar();
    // ---- p1: B cols [32,64); stage B(t+1) chunks 2,3
    rdB(fB1, bT + 4096);
    if (doB) { stage1(B, stB, kB, 2); stage1(B, stB, kB, 3); }
    bar(); waitlg0();
    __builtin_amdgcn_s_setprio(1); mm8(0, 1, fB1); __builtin_amdgcn_s_setprio(0);
    bar();
    // ---- p2: A rows [64,128) overwrite fA; stage A(t+2) chunks 0,2
    rdA(aT + 8192);
    if (doA) { stage1(A, pAcur, kA, 0); stage1(A, pAcur, kA, 2); }
    bar(); waitlg0();
    __builtin_amdgcn_s_setprio(1); mm8(2, 1, fB1); __builtin_amdgcn_s_setprio(0);
    bar();
    // ---- p3: no reads; stage A(t+2) chunks 1,3
    if (doA) { stage1(A, pAcur, kA, 1); stage1(A, pAcur, kA, 3); }
    bar();
    __builtin_amdgcn_s_setprio(1); mm8(2, 0, fB0); __builtin_amdgcn_s_setprio(0);
    if (tailmode == 0) waitvm4(); else if (tailmode == 1) waitvm0();
    bar();
  };

  // prologue: A(t0), B(t0), A(t1) staged; A(t1) stays in flight
  stage1(A, pA[0], 0, 0); stage1(A, pA[0], 0, 1);
  stage1(A, pA[0], 0, 2); stage1(A, pA[0], 0, 3);
  stage1(B, pB[0], 0, 0); stage1(B, pB[0], 0, 1);
  stage1(B, pB[0], 0, 2); stage1(B, pB[0], 0, 3);
  stage1(A, pA[1], 64, 0); stage1(A, pA[1], 64, 1);
  stage1(A, pA[1], 64, 2); stage1(A, pA[1], 64, 3);
  waitvm4(); bar();

#pragma unroll 1
  for (int t = 0; t < 30; t += 2) {
    tile4(aT0, bT0, pA[0], pB[1], (t + 1) * 64, true, (t + 2) * 64, true, 0);
    tile4(aT1, bT1, pA[1], pB[0], (t + 2) * 64, true, (t + 3) * 64, true, 0);
  }
  tile4(aT0, bT0, pA[0], pB[1], 31 * 64, true, 0, false, 1);
  tile4(aT1, bT1, pA[1], nullptr, 0, false, 0, false, 2);
}

// C/D layout 32x32 (HW-verified): col=lane&31, row=(reg&3)+8*(reg>>2)+4*hi
__device__ __forceinline__ void store256(h16_t* __restrict__ C,
                                         f32x16 acc[4][2], int bm, int bn)
{
  const int tid = threadIdx.x, wid = tid >> 6, lane = tid & 63;
  const int wr2 = wid >> 2, wcid = wid & 3;
  const int l31 = lane & 31, hi = lane >> 5;
  const int gr0 = bm * 256 + wr2 * 128 + 4 * hi;
  const int gc0 = bn * 256 + wcid * 64 + l31;
#pragma unroll
  for (int am = 0; am < 4; am++)
#pragma unroll
    for (int r = 0; r < 16; r++) {
      const int row = gr0 + am * 32 + (r & 3) + 8 * (r >> 2);
      const long long ro = (long long)row * HDIM;
#pragma unroll
      for (int nj = 0; nj < 2; nj++)
        C[ro + gc0 + nj * 32] = (h16_t)acc[am][nj][r];
    }
}

// XCD-grouped bijective swizzle for 256-block launches (XCD = flat%8):
// XCD c gets logical ids [c*32, c*32+32) => contiguous bm x all bn =>
// A-panels L2-resident per XCD, B panel streams.
template<int GY>
__device__ __forceinline__ void remap256(int& bn, int& bm, int& z) {
  const int flat = blockIdx.x + 8 * (blockIdx.y + GY * blockIdx.z);
  const int l = (flat & 7) * 32 + (flat >> 3);
  bn = l & 7;
  const int rest = l >> 3;
  bm = rest & (GY - 1);
  z  = rest / GY;
}

// ---------------------------------------------------------------------------
template<int GY>
__global__ __launch_bounds__(512, 1)
void gemm256_b(const h16_t* __restrict__ Ab, const h16_t* __restrict__ Bb,
               h16_t* __restrict__ Cb, long long sAz, long long sBz, long long sCz)
{
  __shared__ __align__(16) h16_t smem[4 * 16384];
  int bn, bm, z;
  remap256<GY>(bn, bm, z);
  const h16_t* A = Ab + (long long)z * sAz + (long long)bm * 256 * HDIM;
  const h16_t* B = Bb + (long long)z * sBz + (long long)bn * 256 * HDIM;
  f32x16 acc[4][2];
  core256(A, B, smem, acc);
  store256(Cb + (long long)z * sCz, acc, bm, bn);
}

// standalone softmax: in-place on sc rows; 8 rows/block (one 2048-wide row
// per 64-lane wave, 32 f16/lane). Zero LDS -> full occupancy, was
// serializing as a 1-block/CU tail inside the 128KB-LDS GEMM kernel (R4).
__global__ __launch_bounds__(512)
void softmax_kernel(h16_t* __restrict__ sc)
{
  const int tid = threadIdx.x, wid = tid >> 6, lane = tid & 63;
  const long long row = (long long)blockIdx.x * 8 + wid;
  h16_t* s = sc + row * HDIM;
  h16x8 raw[4];
#pragma unroll
  for (int i = 0; i < 4; i++) raw[i] = ((const h16x8*)s)[i * 64 + lane];
  float v[32];
  float mx = -3.0e38f;
#pragma unroll
  for (int i = 0; i < 32; i++) { v[i] = (float)raw[i >> 3][i & 7]; mx = fmaxf(mx, v[i]); }
#pragma unroll
  for (int off = 32; off; off >>= 1) mx = fmaxf(mx, __shfl_xor(mx, off, 64));
  float sum = 0.f;
#pragma unroll
  for (int i = 0; i < 32; i++) { v[i] = __expf(v[i] - mx); sum += v[i]; }
#pragma unroll
  for (int off = 32; off; off >>= 1) sum += __shfl_xor(sum, off, 64);
  const float inv = 1.0f / sum;
#pragma unroll
  for (int i = 0; i < 4; i++) {
    h16x8 o;
#pragma unroll
    for (int j = 0; j < 8; j++) o[j] = (h16_t)(v[i * 8 + j] * inv);
    ((h16x8*)s)[i * 64 + lane] = o;
  }
}

// final: out += sum relu(P @ u) . colsum(W2)  (32 colsum partials)
__global__ __launch_bounds__(512, 1)
void gemm256_final(const h16_t* __restrict__ P, const h16_t* __restrict__ utb,
                   const float* __restrict__ w2p, float* __restrict__ outp)
{
  __shared__ __align__(16) h16_t smem[4 * 16384];
  int bn, bm, z;
  remap256<8>(bn, bm, z);
  const long long HH = (long long)HDIM * HDIM;
  const h16_t* A = P   + (long long)z * HH + (long long)bm * 256 * HDIM;
  const h16_t* B = utb + (long long)z * HH + (long long)bn * 256 * HDIM;
  f32x16 acc[4][2];
  core256(A, B, smem, acc);

  const int tid = threadIdx.x, wid = tid >> 6, lane = tid & 63;
  const int wcid = wid & 3, l31 = lane & 31;
  const int gc0 = bn * 256 + wcid * 64 + l31;
  float w2j[2];
#pragma unroll
  for (int nj = 0; nj < 2; nj++) {
    const int col = gc0 + nj * 32;
    float s = 0.f;
#pragma unroll
    for (int c = 0; c < 32; c++) s += w2p[c * HDIM + col];
    w2j[nj] = s;
  }
  float s = 0.f;
#pragma unroll
  for (int am = 0; am < 4; am++)
#pragma unroll
    for (int nj = 0; nj < 2; nj++)
#pragma unroll
      for (int r = 0; r < 16; r++) {
        const float vv = acc[am][nj][r];
        s += (vv > 0.f) ? vv * w2j[nj] : 0.f;
      }
#pragma unroll
  for (int off = 32; off; off >>= 1) s += __shfl_down(s, off, 64);
  __shared__ float red[8];
  if (lane == 0) red[wid] = s;
  __syncthreads();
  if (tid == 0) {
    float t = 0.f;
#pragma unroll
    for (int w = 0; w < 8; w++) t += red[w];
    atomicAdd(outp, t);
  }
}

// ---------------------------------------------------------------------------
// mega-prologue: vectorized transpose (64x64 f32 LDS tile, float4 loads,
// h16x8 stores), 32-partial colsum. Segments by blockIdx.x.
__global__ __launch_bounds__(256)
void prologue_kernel(const float* __restrict__ x,  const float* __restrict__ Wq,
                     const float* __restrict__ Wk, const float* __restrict__ Wv,
                     const float* __restrict__ Wo, const float* __restrict__ W1,
                     const float* __restrict__ W2,
                     h16_t* __restrict__ xb,  h16_t* __restrict__ WkT,
                     h16_t* __restrict__ WvT, h16_t* __restrict__ WqT,
                     h16_t* __restrict__ Wob, h16_t* __restrict__ W1b,
                     float* __restrict__ w2p, float* __restrict__ outp)
{
  const int t = threadIdx.x;
  int b = blockIdx.x;
  if (b < 16384) {                       // x: fp32 -> f16, 4/thread
    const long long i = (long long)b * 256 + t;
    const float4 v = ((const float4*)x)[i];
    h16x4 o;
    o[0] = (h16_t)v.x; o[1] = (h16_t)v.y; o[2] = (h16_t)v.z; o[3] = (h16_t)v.w;
    ((h16x4*)xb)[i] = o;
    return;
  }
  b -= 16384;
  if (b < 3072) {                        // Wk,Wv,Wq transposed converts, 64x64
    const float* src; h16_t* dst;
    const int w = b >> 10, b10 = b & 1023;
    if (w == 0)      { src = Wk; dst = WkT; }
    else if (w == 1) { src = Wv; dst = WvT; }
    else             { src = Wq; dst = WqT; }
    __shared__ float tl[64][65];
    const int bx = (b10 & 31) * 64, by = (b10 >> 5) * 64;
#pragma unroll
    for (int i = 0; i < 4; i++) {        // float4 loads: 256B/row contiguous
      const int idx = i * 256 + t;
      const int r = idx >> 4, c4 = idx & 15;
      const float4 v = *(const float4*)(src + (long long)(by + r) * 2048 + bx + c4 * 4);
      tl[r][c4 * 4 + 0] = v.x; tl[r][c4 * 4 + 1] = v.y;
      tl[r][c4 * 4 + 2] = v.z; tl[r][c4 * 4 + 3] = v.w;
    }
    __syncthreads();
#pragma unroll
    for (int i = 0; i < 2; i++) {        // h16x8 stores: 128B contiguous
      const int idx = i * 256 + t;
      const int c = idx >> 3, r8 = (idx & 7) * 8;
      h16x8 o;
#pragma unroll
      for (int j = 0; j < 8; j++) o[j] = (h16_t)tl[r8 + j][c];
      *(h16x8*)(dst + (long long)(bx + c) * 2048 + by + r8) = o;
    }
    return;
  }
  b -= 3072;
  if (b < 8192) {                        // Wo, W1 plain converts
    const float* src = (b < 4096) ? Wo : W1;
    h16_t* dst = (b < 4096) ? Wob : W1b;
    const long long i = (long long)(b & 4095) * 256 + t;
    const float4 v = ((const float4*)src)[i];
    h16x4 o;
    o[0] = (h16_t)v.x; o[1] = (h16_t)v.y; o[2] = (h16_t)v.z; o[3] = (h16_t)v.w;
    ((h16x4*)dst)[i] = o;
    return;
  }
  b -= 8192;
  if (b < 256) {                         // W2 colsum partials (32 x 64 rows)
    const int c = b >> 3;
    const int h = (b & 7) * 256 + t;
    float s = 0.f;
#pragma unroll 4
    for (int d = 0; d < 64; d++) s += W2[(long long)(c * 64 + d) * 2048 + h];
    w2p[c * 2048 + h] = s;
    return;
  }
  b -= 256;
  if (b == 0 && t == 0) outp[0] = 0.f;   // zero the output accumulator
}

// ---------------------------------------------------------------------------
extern "C" void kernel_launch(void* const* d_in, const int* in_sizes, int n_in,
                              void* d_out, int out_size, void* d_ws, size_t ws_size,
                              hipStream_t stream)
{
  const float* x  = (const float*)d_in[0];
  const float* Wq = (const float*)d_in[1];
  const float* Wk = (const float*)d_in[2];
  const float* Wv = (const float*)d_in[3];
  const float* Wo = (const float*)d_in[4];
  const float* W1 = (const float*)d_in[5];
  const float* W2 = (const float*)d_in[6];
  float* out = (float*)d_out;

  const long long HH = (long long)HDIM * HDIM;   // 4,194,304
  const long long XE = (long long)MROWS * HDIM;  // 16,777,216

  // Algebra: score = x (Wq^T Wk) x^T;  h = relu(P x (W1 Wo Wv)^T);
  //          out = sum h.colsum(W2)
  char* p = (char*)d_ws;
  h16_t* xb   = (h16_t*)p; p += XE * 2;
  h16_t* WkT  = (h16_t*)p; p += HH * 2;
  h16_t* WvT  = (h16_t*)p; p += HH * 2;
  h16_t* WqT  = (h16_t*)p; p += HH * 2;
  h16_t* Wob  = (h16_t*)p; p += HH * 2;
  h16_t* WqkT = (h16_t*)p; p += HH * 2;
  h16_t* GT   = (h16_t*)p; p += HH * 2;
  h16_t* W1b  = (h16_t*)p; p += HH * 2;
  h16_t* Wvow = (h16_t*)p; p += HH * 2;
  h16_t* tb   = (h16_t*)p; p += XE * 2;  // t, then uT
  h16_t* sc   = (h16_t*)p; p += XE * 2;  // score -> P in place
  float* w2p  = (float*)p; p += 32 * HDIM * 4;

  const dim3 b256(256), b512(512);

  // 1. mega-prologue: converts, transposes, colsum, zero-out
  prologue_kernel<<<dim3(16384 + 3072 + 8192 + 256 + 1), b256, 0, stream>>>(
      x, Wq, Wk, Wv, Wo, W1, W2, xb, WkT, WvT, WqT, Wob, W1b, w2p, out);

  // 2. batched fold: WqkT = (Wq^T Wk)^T ; GT = (Wo Wv)^T   (128^2 kernel)
  gemm_b<<<dim3(16, 16, 2), b256, 0, stream>>>(WkT, WqT, WqkT, HH, HH, HH);

  // 3. Wvow = W1.G fold (128^2 kernel, 256 balanced blocks)
  gemm_b<<<dim3(16, 16, 1), b256, 0, stream>>>(W1b, GT, Wvow, 0, 0, 0);

  // 4. t = x@Wqk   (256^2 8-phase, 8x32 = 256 blocks, 1/CU)
  gemm256_b<32><<<dim3(8, 32, 1), b512, 0, stream>>>(xb, WqkT, tb, 0, 0, 0);

  // 5. score[b,i,j] = sum_e t[b,i,e]*x[b,j,e]   (256 blocks)
  gemm256_b<8><<<dim3(8, 8, 4), b512, 0, stream>>>(tb, xb, sc, HH, HH, HH);

  // 6. softmax(sc) in place — zero-LDS, full-occupancy dispatch
  softmax_kernel<<<dim3(1024), b512, 0, stream>>>(sc);

  // 7. uT[b,e,j] = sum_h Wvow[e,h]*x[b,j,h]  (pure GEMM now)
  gemm256_b<8><<<dim3(8, 8, 4), b512, 0, stream>>>(Wvow, xb, tb, 0, HH, HH);

  // 8. out += sum relu(P @ u) . w2
  gemm256_final<<<dim3(8, 8, 4), b512, 0, stream>>>(sc, tb, w2p, out);
}